// Round 6
// baseline (358.360 us; speedup 1.0000x reference)
//
#include <hip/hip_runtime.h>

#define B_   4
#define C_   256
#define C8_  32
#define N_   4096
#define JS   2                 // key split: js0 -> fp32 in d_out, js1 -> bf16 pnum1
#define NJ   (N_ / JS)         // 2048 keys per attn block
#define NTILE (NJ / 32)        // 64 j-tiles per attn block
#define BCN  ((size_t)B_ * C_ * N_)   // 4,194,304

typedef __attribute__((ext_vector_type(8))) short bf16x8;
typedef __attribute__((ext_vector_type(4))) short bf16x4;
typedef __attribute__((ext_vector_type(4))) float f32x4;

__device__ inline short f2bf(float f) {
    union { float f; unsigned u; } v; v.f = f;
    unsigned r = v.u + 0x7FFFu + ((v.u >> 16) & 1u);   // RNE
    return (short)(r >> 16);
}
__device__ inline float bf2f(short s) {
    union { unsigned u; float f; } v; v.u = ((unsigned)(unsigned short)s) << 16;
    return v.f;
}

// K=16 bf16 MFMA via inline asm (ISA-documented on gfx950: A 2 regs, B 2, C/D 4).
// Register-only op; dependencies carried through operands, so scheduling is safe.
__device__ inline f32x4 mfma16(bf16x4 a, bf16x4 b, f32x4 c) {
    asm("v_mfma_f32_16x16x16_bf16 %0, %1, %2, %0" : "+v"(c) : "v"(a), "v"(b));
    return c;
}

// ---------------------------------------------------------------------------
// Kernel 0: prep. blocks [0,1024): transpose x -> xT[B][N][C] bf16 (64x64
// tiles via LDS). blocks [1024,1064): W fp32 -> Wall[320][256] bf16
// (rows 0-31 Wq, 32-63 Wk, 64-319 Wv). block 1064: bias gather ball[320].
// ---------------------------------------------------------------------------
__global__ __launch_bounds__(256) void prep_kernel(
    const float* __restrict__ x,
    const float* __restrict__ Wq, const float* __restrict__ bq,
    const float* __restrict__ Wk, const float* __restrict__ bk,
    const float* __restrict__ Wv, const float* __restrict__ bv,
    short* __restrict__ xT, short* __restrict__ Wall, float* __restrict__ ball)
{
    const int blk = blockIdx.x;
    const int t   = threadIdx.x;
    if (blk < 1024) {
        __shared__ float tile[64 * 67];
        const int b   = blk >> 8;
        const int rem = blk & 255;
        const int c0  = (rem >> 6) << 6;
        const int n0  = (rem & 63) << 6;
        const float* xb = x + ((size_t)b * C_ + c0) * N_ + n0;
        #pragma unroll
        for (int i = 0; i < 4; i++) {
            int e = t + i * 256;                 // 1024 float4 = 64 rows x 16
            int c = e >> 4, n4 = (e & 15) * 4;
            float4 v = *(const float4*)(xb + (size_t)c * N_ + n4);
            float* dst = &tile[c * 67 + n4];
            dst[0] = v.x; dst[1] = v.y; dst[2] = v.z; dst[3] = v.w;
        }
        __syncthreads();
        short* xo = xT + ((size_t)b * N_ + n0) * C_ + c0;
        #pragma unroll
        for (int i = 0; i < 4; i++) {
            int e = t + i * 256;
            int n = e >> 4, c4 = (e & 15) * 4;
            short4 s;
            s.x = f2bf(tile[(c4 + 0) * 67 + n]);
            s.y = f2bf(tile[(c4 + 1) * 67 + n]);
            s.z = f2bf(tile[(c4 + 2) * 67 + n]);
            s.w = f2bf(tile[(c4 + 3) * 67 + n]);
            *(short4*)(xo + (size_t)n * C_ + c4) = s;
        }
    } else if (blk < 1064) {
        const int base = (blk - 1024) * 2048 + t * 8;   // 40*2048 = 320*256
        const int r = base >> 8, cc = base & 255;
        const float* src = (r < 32) ? &Wq[r * C_ + cc]
                         : (r < 64) ? &Wk[(r - 32) * C_ + cc]
                                    : &Wv[(r - 64) * C_ + cc];
        const float4 a  = *(const float4*)src;
        const float4 b4 = *(const float4*)(src + 4);
        short4 s1, s2;
        s1.x = f2bf(a.x);  s1.y = f2bf(a.y);  s1.z = f2bf(a.z);  s1.w = f2bf(a.w);
        s2.x = f2bf(b4.x); s2.y = f2bf(b4.y); s2.z = f2bf(b4.z); s2.w = f2bf(b4.w);
        *(short4*)&Wall[base]     = s1;
        *(short4*)&Wall[base + 4] = s2;
    } else {
        for (int i = t; i < 320; i += 256)
            ball[i] = (i < 32) ? bq[i] : (i < 64) ? bk[i - 32] : bv[i - 64];
    }
}

// ---------------------------------------------------------------------------
// Kernel 1: MFMA projections. out[co][p] = sum_c W[co][c] x[c][p], co in 0..319.
// Grid (N/64, 2, B), 256 thr. Wave = 16 px, 10 co-tiles, K=256 in 8 steps.
// v7: V written in a K=16-fragment-friendly interleave within each 32-column
// block: column n stored at n2 = base32 | ((n>>2)&3)*8 | ((n>>4)&1)*4 | (n&3),
// so one dwordx4 V load in attn yields both K=16 A-fragments (j and j+16).
// ---------------------------------------------------------------------------
__global__ __launch_bounds__(256, 2) void proj_kernel(
    const short* __restrict__ xT, const short* __restrict__ Wall,
    const float* __restrict__ ball,
    short* __restrict__ qws, short* __restrict__ kws, short* __restrict__ vws)
{
    const int n0    = blockIdx.x * 64;
    const int split = blockIdx.y;
    const int b     = blockIdx.z;
    const int t     = threadIdx.x;
    const int w     = t >> 6, lane = t & 63, l16 = lane & 15, quad = lane >> 4;
    const int n     = n0 + w * 16 + l16;

    bf16x8 bfr[8];
    const short* xrow = xT + ((size_t)b * N_ + n) * C_;
    #pragma unroll
    for (int k = 0; k < 8; k++) bfr[k] = *(const bf16x8*)(xrow + k * 32 + quad * 8);

    f32x4 acc[10];
    #pragma unroll
    for (int i = 0; i < 10; i++) acc[i] = (f32x4){0.f, 0.f, 0.f, 0.f};

    const int gct0 = split * 10;
    #pragma unroll
    for (int k = 0; k < 8; k++) {
        #pragma unroll
        for (int ct = 0; ct < 10; ct++) {
            const bf16x8 af = *(const bf16x8*)
                &Wall[(size_t)((gct0 + ct) * 16 + l16) * C_ + k * 32 + quad * 8];
            acc[ct] = __builtin_amdgcn_mfma_f32_16x16x32_bf16(af, bfr[k], acc[ct], 0, 0, 0);
        }
    }

    // V column permutation (bijective within each 32 block)
    const int n2 = (n & ~31) | (((n >> 2) & 3) << 3) | (((n >> 4) & 1) << 2) | (n & 3);

    #pragma unroll
    for (int ct = 0; ct < 10; ct++) {
        const int gct = gct0 + ct;
        const int cb  = gct * 16 + quad * 4;
        float v0 = acc[ct][0] + ball[cb + 0];
        float v1 = acc[ct][1] + ball[cb + 1];
        float v2 = acc[ct][2] + ball[cb + 2];
        float v3 = acc[ct][3] + ball[cb + 3];
        if (gct < 2) {
            short4 s; s.x = f2bf(v0); s.y = f2bf(v1); s.z = f2bf(v2); s.w = f2bf(v3);
            *(short4*)&qws[((size_t)b * N_ + n) * C8_ + cb] = s;
        } else if (gct < 4) {
            short4 s; s.x = f2bf(v0); s.y = f2bf(v1); s.z = f2bf(v2); s.w = f2bf(v3);
            *(short4*)&kws[((size_t)b * N_ + n) * C8_ + (cb - 32)] = s;
        } else {
            const int c = cb - 64;
            vws[((size_t)b * C_ + c + 0) * N_ + n2] = f2bf(v0);
            vws[((size_t)b * C_ + c + 1) * N_ + n2] = f2bf(v1);
            vws[((size_t)b * C_ + c + 2) * N_ + n2] = f2bf(v2);
            vws[((size_t)b * C_ + c + 3) * N_ + n2] = f2bf(v3);
        }
    }
}

// ---------------------------------------------------------------------------
// Kernel 2: MFMA flash attention, v7: BARRIER-FREE, LDS-FREE per-wave flash.
// Evidence v0-v6: time/work ~const (~3000cy per 128qx32j/CU) with all pipes
// <25% regardless of LDS traffic, barrier count, drain type, VMEM count,
// occupancy -> the floor is the per-tile cross-wave phase lock (every wave
// on the CU sits in the same serial softmax/LDS/barrier stretch; matrix pipe
// starves). Fix: each wave owns 16 q x ALL 256 c (acc = 64 VGPR), P stays
// in registers -> zero cross-wave dependency, zero barriers, zero LDS.
//   - QK: S^T frag (j=quad*4+r, q=l16) from 2x mfma_16x16x32 (unchanged).
//   - PV: the S^T frag IS the B-operand layout of K=16 mfma_16x16x16_bf16.
//     P packed in-reg (pfa=exp(s0), pfb=exp(s1)); per c-frag 2 K=16 MFMAs.
//     V pre-interleaved by proj so one dwordx4 = both K=16 A-frags.
//   - K double-buffered in regs (ping-pong macro, static indexing).
//   - T5 setprio around the PV cluster (independent-wave structure = the
//     regime where it measured +4-7%, m191).
// Numerics: QK identical; PV reassociated (2xK=16 vs K=32) - same-magnitude
// rounding as previous passing variants.
// ---------------------------------------------------------------------------
#define TILE_BODY(TILE, KC0, KC1, KN0, KN1)                                   \
  {                                                                           \
    const short* vb = vbase + (TILE) * 32;                                    \
    bf16x8 vraw[16];                                                          \
    _Pragma("unroll") for (int ct = 0; ct < 16; ct++)                         \
      vraw[ct] = *(const bf16x8*)(vb + (size_t)(ct * 16 + l16) * N_ + quad * 8);\
    f32x4 s0 = __builtin_amdgcn_mfma_f32_16x16x32_bf16(                       \
        KC0, qf, (f32x4){0.f, 0.f, 0.f, 0.f}, 0, 0, 0);                       \
    f32x4 s1 = __builtin_amdgcn_mfma_f32_16x16x32_bf16(                       \
        KC1, qf, (f32x4){0.f, 0.f, 0.f, 0.f}, 0, 0, 0);                       \
    /* K prefetch for next tile into the other buffer (clamped) */            \
    {                                                                         \
      const int tn = ((TILE) + 1 < NTILE) ? (TILE) + 1 : (TILE);              \
      const short* kb = kbase + (size_t)(tn * 32) * C8_;                      \
      KN0 = *(const bf16x8*)(kb + (size_t)l16 * C8_ + quad * 8);              \
      KN1 = *(const bf16x8*)(kb + (size_t)(16 + l16) * C8_ + quad * 8);       \
    }                                                                         \
    /* softmax numerator (no max: scores bounded ~O(3) at this scale) */      \
    float pe[8];                                                              \
    _Pragma("unroll") for (int r = 0; r < 4; r++) {                           \
      pe[r] = __expf(s0[r]); lsum += pe[r];                                   \
    }                                                                         \
    _Pragma("unroll") for (int r = 0; r < 4; r++) {                           \
      pe[4 + r] = __expf(s1[r]); lsum += pe[4 + r];                           \
    }                                                                         \
    bf16x4 pfa, pfb;                                                          \
    pfa[0] = f2bf(pe[0]); pfa[1] = f2bf(pe[1]);                               \
    pfa[2] = f2bf(pe[2]); pfa[3] = f2bf(pe[3]);                               \
    pfb[0] = f2bf(pe[4]); pfb[1] = f2bf(pe[5]);                               \
    pfb[2] = f2bf(pe[6]); pfb[3] = f2bf(pe[7]);                               \
    __builtin_amdgcn_s_setprio(1);                                            \
    _Pragma("unroll") for (int ct = 0; ct < 16; ct++) {                       \
      const bf16x4 va = __builtin_shufflevector(vraw[ct], vraw[ct], 0, 1, 2, 3);\
      const bf16x4 vh = __builtin_shufflevector(vraw[ct], vraw[ct], 4, 5, 6, 7);\
      acc[ct] = mfma16(va, pfa, acc[ct]);                                     \
      acc[ct] = mfma16(vh, pfb, acc[ct]);                                     \
    }                                                                         \
    __builtin_amdgcn_s_setprio(0);                                            \
  }

__global__ __launch_bounds__(256, 2) void attn_kernel(
    const short* __restrict__ qws, const short* __restrict__ kws,
    const short* __restrict__ vws,
    float* __restrict__ out, short* __restrict__ pnum1, float* __restrict__ pl)
{
    const int blk = blockIdx.x;
    const int b   = blk & 3;
    const int js  = (blk >> 2) & 1;
    const int qc  = blk >> 3;            // 0..63
    const int t   = threadIdx.x;
    const int w   = t >> 6, lane = t & 63, l16 = lane & 15, quad = lane >> 4;
    const int q   = qc * 64 + w * 16 + l16;   // this wave's q row for this lane

    const bf16x8 qf = *(const bf16x8*)&qws[((size_t)b * N_ + q) * C8_ + quad * 8];

    f32x4 acc[16];                       // [256 c][16 q] for this wave
    #pragma unroll
    for (int i = 0; i < 16; i++) acc[i] = (f32x4){0.f, 0.f, 0.f, 0.f};
    float lsum = 0.f;

    const short* kbase = kws + ((size_t)b * N_ + js * NJ) * C8_;
    const short* vbase = vws + (size_t)b * C_ * N_ + js * NJ;

    // prologue: K fragments for tile 0
    bf16x8 kfA0 = *(const bf16x8*)(kbase + (size_t)l16 * C8_ + quad * 8);
    bf16x8 kfA1 = *(const bf16x8*)(kbase + (size_t)(16 + l16) * C8_ + quad * 8);
    bf16x8 kfB0, kfB1;

    #pragma unroll 1
    for (int tile = 0; tile < NTILE; tile += 2) {
        TILE_BODY(tile,     kfA0, kfA1, kfB0, kfB1);
        TILE_BODY(tile + 1, kfB0, kfB1, kfA0, kfA1);
    }

    // denominator partial: lane's pe covered j=quad*4+r and 16+quad*4+r per
    // tile; reduce over quads -> per-q sum for this js half.
    lsum += __shfl_xor(lsum, 16, 64);
    lsum += __shfl_xor(lsum, 32, 64);
    if (quad == 0) pl[(size_t)js * 16384 + (size_t)b * N_ + q] = lsum;

    // numerator partial: js0 -> fp32 into out, js1 -> bf16 into pnum1.
    // acc[ct] D-layout: row c = ct*16 + quad*4 + r, col q = l16.
    if (js == 0) {
        float* ob = out + (size_t)b * C_ * N_;
        #pragma unroll
        for (int ct = 0; ct < 16; ++ct)
            #pragma unroll
            for (int r = 0; r < 4; ++r) {
                const int c = ct * 16 + quad * 4 + r;
                ob[(size_t)c * N_ + q] = acc[ct][r];
            }
    } else {
        short* pb1 = pnum1 + (size_t)b * C_ * N_;
        #pragma unroll
        for (int ct = 0; ct < 16; ++ct)
            #pragma unroll
            for (int r = 0; r < 4; ++r) {
                const int c = ct * 16 + quad * 4 + r;
                pb1[(size_t)c * N_ + q] = f2bf(acc[ct][r]);
            }
    }
}

// ---------------------------------------------------------------------------
// Kernel 3: linv = 1/(pl0+pl1).  Kernel 4: out = g*(out + pnum1)*linv + x.
// ---------------------------------------------------------------------------
__global__ __launch_bounds__(256) void lred_kernel(
    const float* __restrict__ pl, float* __restrict__ linv)
{
    const int i = blockIdx.x * 256 + threadIdx.x;   // over B*N = 16384
    linv[i] = 1.0f / (pl[i] + pl[16384 + i]);
}

__global__ __launch_bounds__(256) void combine_kernel(
    const short* __restrict__ pnum1, const float* __restrict__ linv,
    const float* __restrict__ x, const float* __restrict__ gamma,
    float* __restrict__ out)
{
    const size_t i4 = ((size_t)blockIdx.x * 256 + threadIdx.x) * 4;   // < BCN
    const float4 nv = *(const float4*)(out + i4);
    const short4 n1 = *(const short4*)(pnum1 + i4);
    const float4 xv = *(const float4*)(x + i4);
    const int   bn  = (int)((i4 >> 20) * 4096 + (i4 & 4095));         // b*N + n
    const float4 lv = *(const float4*)(linv + bn);
    const float g0 = gamma[0];
    float4 o;
    o.x = g0 * ((nv.x + bf2f(n1.x)) * lv.x) + xv.x;
    o.y = g0 * ((nv.y + bf2f(n1.y)) * lv.y) + xv.y;
    o.z = g0 * ((nv.z + bf2f(n1.z)) * lv.z) + xv.z;
    o.w = g0 * ((nv.w + bf2f(n1.w)) * lv.w) + xv.w;
    *(float4*)(out + i4) = o;
}

extern "C" void kernel_launch(void* const* d_in, const int* in_sizes, int n_in,
                              void* d_out, int out_size, void* d_ws, size_t ws_size,
                              hipStream_t stream)
{
    const float* x     = (const float*)d_in[0];
    const float* Wq    = (const float*)d_in[1];
    const float* bq    = (const float*)d_in[2];
    const float* Wk    = (const float*)d_in[3];
    const float* bk    = (const float*)d_in[4];
    const float* Wv    = (const float*)d_in[5];
    const float* bv    = (const float*)d_in[6];
    const float* gamma = (const float*)d_in[7];
    float* out = (float*)d_out;

    // ws layout, 18.4 MiB total (proven-safe).
    // pnum1 overlaps xT: xT dead after proj_kernel, pnum1 written by attn.
    char* base = (char*)d_ws;
    short* vws   = (short*)(base);                      // 8 MB  [B][256][N] @ 0x0
    short* qws   = (short*)(base + 0x800000);           // 1 MB  [B][N][32]
    short* kws   = (short*)(base + 0x900000);           // 1 MB  [B][N][32]
    float* pl    = (float*)(base + 0xA00000);           // 128 KB [2][B*N]
    float* linv  = (float*)(base + 0xA20000);           // 64 KB
    short* Wall  = (short*)(base + 0xA30000);           // 160 KB
    float* ball  = (float*)(base + 0xA58000);           // 1.25 KB
    short* xT    = (short*)(base + 0xA60000);           // 8 MB  [B][N][256]
    short* pnum1 = (short*)(base + 0xA60000);           // 8 MB  [B][256][N] (over xT)

    prep_kernel<<<1065, 256, 0, stream>>>(x, Wq, bq, Wk, bk, Wv, bv, xT, Wall, ball);
    proj_kernel<<<dim3(N_ / 64, 2, B_), 256, 0, stream>>>(xT, Wall, ball, qws, kws, vws);
    attn_kernel<<<512, 256, 0, stream>>>(qws, kws, vws, out, pnum1, pl);
    lred_kernel<<<64, 256, 0, stream>>>(pl, linv);
    combine_kernel<<<4096, 256, 0, stream>>>(pnum1, linv, x, gamma, out);
}

// Round 7
// 166.650 us; speedup vs baseline: 2.1504x; 2.1504x over previous
//
#include <hip/hip_runtime.h>

#define B_   4
#define C_   256
#define C8_  32
#define N_   4096
#define JS   2                 // key split: js0 -> fp32 in d_out, js1 -> bf16 pnum1
#define NJ   (N_ / JS)         // 2048 keys per attn block
#define KB2  128               // j per tile
#define NT2  (NJ / KB2)        // 16 j-tiles per attn block
#define SUBT 8192              // shorts per V subtile: 256 c x 32 j
#define BCN  ((size_t)B_ * C_ * N_)   // 4,194,304

typedef __attribute__((ext_vector_type(8))) short bf16x8;
typedef __attribute__((ext_vector_type(4))) float f32x4;

__device__ inline short f2bf(float f) {
    union { float f; unsigned u; } v; v.f = f;
    unsigned r = v.u + 0x7FFFu + ((v.u >> 16) & 1u);   // RNE
    return (short)(r >> 16);
}
__device__ inline float bf2f(short s) {
    union { unsigned u; float f; } v; v.u = ((unsigned)(unsigned short)s) << 16;
    return v.f;
}

// ---------------------------------------------------------------------------
// Kernel 0: prep. blocks [0,1024): transpose x -> xT[B][N][C] bf16 (64x64
// tiles via LDS). blocks [1024,1064): W fp32 -> Wall[320][256] bf16
// (rows 0-31 Wq, 32-63 Wk, 64-319 Wv). block 1064: bias gather ball[320].
// ---------------------------------------------------------------------------
__global__ __launch_bounds__(256) void prep_kernel(
    const float* __restrict__ x,
    const float* __restrict__ Wq, const float* __restrict__ bq,
    const float* __restrict__ Wk, const float* __restrict__ bk,
    const float* __restrict__ Wv, const float* __restrict__ bv,
    short* __restrict__ xT, short* __restrict__ Wall, float* __restrict__ ball)
{
    const int blk = blockIdx.x;
    const int t   = threadIdx.x;
    if (blk < 1024) {
        __shared__ float tile[64 * 67];
        const int b   = blk >> 8;
        const int rem = blk & 255;
        const int c0  = (rem >> 6) << 6;
        const int n0  = (rem & 63) << 6;
        const float* xb = x + ((size_t)b * C_ + c0) * N_ + n0;
        #pragma unroll
        for (int i = 0; i < 4; i++) {
            int e = t + i * 256;                 // 1024 float4 = 64 rows x 16
            int c = e >> 4, n4 = (e & 15) * 4;
            float4 v = *(const float4*)(xb + (size_t)c * N_ + n4);
            float* dst = &tile[c * 67 + n4];
            dst[0] = v.x; dst[1] = v.y; dst[2] = v.z; dst[3] = v.w;
        }
        __syncthreads();
        short* xo = xT + ((size_t)b * N_ + n0) * C_ + c0;
        #pragma unroll
        for (int i = 0; i < 4; i++) {
            int e = t + i * 256;
            int n = e >> 4, c4 = (e & 15) * 4;
            short4 s;
            s.x = f2bf(tile[(c4 + 0) * 67 + n]);
            s.y = f2bf(tile[(c4 + 1) * 67 + n]);
            s.z = f2bf(tile[(c4 + 2) * 67 + n]);
            s.w = f2bf(tile[(c4 + 3) * 67 + n]);
            *(short4*)(xo + (size_t)n * C_ + c4) = s;
        }
    } else if (blk < 1064) {
        const int base = (blk - 1024) * 2048 + t * 8;   // 40*2048 = 320*256
        const int r = base >> 8, cc = base & 255;
        const float* src = (r < 32) ? &Wq[r * C_ + cc]
                         : (r < 64) ? &Wk[(r - 32) * C_ + cc]
                                    : &Wv[(r - 64) * C_ + cc];
        const float4 a  = *(const float4*)src;
        const float4 b4 = *(const float4*)(src + 4);
        short4 s1, s2;
        s1.x = f2bf(a.x);  s1.y = f2bf(a.y);  s1.z = f2bf(a.z);  s1.w = f2bf(a.w);
        s2.x = f2bf(b4.x); s2.y = f2bf(b4.y); s2.z = f2bf(b4.z); s2.w = f2bf(b4.w);
        *(short4*)&Wall[base]     = s1;
        *(short4*)&Wall[base + 4] = s2;
    } else {
        for (int i = t; i < 320; i += 256)
            ball[i] = (i < 32) ? bq[i] : (i < 64) ? bk[i - 32] : bv[i - 64];
    }
}

// ---------------------------------------------------------------------------
// Kernel 1: MFMA projections. out[co][p] = sum_c W[co][c] x[c][p], co in 0..319.
// Grid (N/64, 2, B), 256 thr. Wave = 16 px, 10 co-tiles, K=256 in 8 steps.
// v8: V written TILE-CONTIGUOUS: vws[[b*2+js][subtile(n>>5)][c][j(n&31)]],
// 8192 shorts per subtile, so attn's V fragment loads are contiguous 1KB.
// ---------------------------------------------------------------------------
__global__ __launch_bounds__(256, 2) void proj_kernel(
    const short* __restrict__ xT, const short* __restrict__ Wall,
    const float* __restrict__ ball,
    short* __restrict__ qws, short* __restrict__ kws, short* __restrict__ vws)
{
    const int n0    = blockIdx.x * 64;
    const int split = blockIdx.y;
    const int b     = blockIdx.z;
    const int t     = threadIdx.x;
    const int w     = t >> 6, lane = t & 63, l16 = lane & 15, quad = lane >> 4;
    const int n     = n0 + w * 16 + l16;

    bf16x8 bfr[8];
    const short* xrow = xT + ((size_t)b * N_ + n) * C_;
    #pragma unroll
    for (int k = 0; k < 8; k++) bfr[k] = *(const bf16x8*)(xrow + k * 32 + quad * 8);

    f32x4 acc[10];
    #pragma unroll
    for (int i = 0; i < 10; i++) acc[i] = (f32x4){0.f, 0.f, 0.f, 0.f};

    const int gct0 = split * 10;
    #pragma unroll
    for (int k = 0; k < 8; k++) {
        #pragma unroll
        for (int ct = 0; ct < 10; ct++) {
            const bf16x8 af = *(const bf16x8*)
                &Wall[(size_t)((gct0 + ct) * 16 + l16) * C_ + k * 32 + quad * 8];
            acc[ct] = __builtin_amdgcn_mfma_f32_16x16x32_bf16(af, bfr[k], acc[ct], 0, 0, 0);
        }
    }

    // V destination: tiled layout [b*2+js][sub][c][j]
    const int js  = n >> 11;            // n / 2048
    const int sub = (n >> 5) & 63;      // 32-j subtile within the js half
    const int jj  = n & 31;
    short* vdst = vws + ((size_t)((b * 2 + js) * 64 + sub)) * SUBT + jj;

    #pragma unroll
    for (int ct = 0; ct < 10; ct++) {
        const int gct = gct0 + ct;
        const int cb  = gct * 16 + quad * 4;
        float v0 = acc[ct][0] + ball[cb + 0];
        float v1 = acc[ct][1] + ball[cb + 1];
        float v2 = acc[ct][2] + ball[cb + 2];
        float v3 = acc[ct][3] + ball[cb + 3];
        if (gct < 2) {
            short4 s; s.x = f2bf(v0); s.y = f2bf(v1); s.z = f2bf(v2); s.w = f2bf(v3);
            *(short4*)&qws[((size_t)b * N_ + n) * C8_ + cb] = s;
        } else if (gct < 4) {
            short4 s; s.x = f2bf(v0); s.y = f2bf(v1); s.z = f2bf(v2); s.w = f2bf(v3);
            *(short4*)&kws[((size_t)b * N_ + n) * C8_ + (cb - 32)] = s;
        } else {
            const int c = cb - 64;
            vdst[(c + 0) * 32] = f2bf(v0);
            vdst[(c + 1) * 32] = f2bf(v1);
            vdst[(c + 2) * 32] = f2bf(v2);
            vdst[(c + 3) * 32] = f2bf(v3);
        }
    }
}

// ---------------------------------------------------------------------------
// Kernel 2: MFMA flash attention, v8 = v5 (benched, passed) with ONE change:
// V reads are tile-contiguous. Cross-variant fit (v0/v2/v3/v5/v7): per-CU
// cost ~66 cy per SCATTERED wave64 dwordx4 (16 discrete 64B segments at V's
// 8KB row stride) -- the TA/L1 segment-service wall; MfmaUtil pinned ~17%
// everywhere because the texture pipe, not MFMA, saturates. With the tiled
// V layout every V fragment load covers one contiguous 1KB span (like K,
// and like the 6.3TB/s u-bench loads). Same fragments, same values, same
// MFMA order -> numerics identical to v5 (absmax was 0.0).
// ---------------------------------------------------------------------------
#define TILE_BODY(TILE, KC, KN, BUF)                                          \
  {                                                                           \
    const short* vb = vbase + (size_t)(TILE) * 4 * SUBT;                      \
    /* V ks0/ks1: issue early (covered by QK+exp+pack; no drain at barrier)*/ \
    bf16x8 vf0[4], vf1[4];                                                    \
    _Pragma("unroll") for (int ct = 0; ct < 4; ct++)                          \
      vf0[ct] = *(const bf16x8*)(vb + 0 * SUBT + (ct*16+l16)*32 + quad*8);    \
    _Pragma("unroll") for (int ct = 0; ct < 4; ct++)                          \
      vf1[ct] = *(const bf16x8*)(vb + 1 * SUBT + (ct*16+l16)*32 + quad*8);    \
    /* QK^T: S^T[j][q] for this wave's 16 q over 128 j */                     \
    f32x4 s[8];                                                               \
    _Pragma("unroll") for (int jf = 0; jf < 8; jf++)                          \
      s[jf] = __builtin_amdgcn_mfma_f32_16x16x32_bf16(KC[jf], qf,             \
              (f32x4){0.f,0.f,0.f,0.f}, 0, 0, 0);                             \
    /* K prefetch for next tile into the other buffer (clamped, branchless)*/ \
    {                                                                         \
      const int tn = ((TILE) + 1 < NT2) ? (TILE) + 1 : (TILE);                \
      const short* kb = kbase + (size_t)(tn * KB2) * C8_;                     \
      _Pragma("unroll") for (int jf = 0; jf < 8; jf++)                        \
        KN[jf] = *(const bf16x8*)(kb + (size_t)(jf*16+l16)*C8_ + quad*8);     \
    }                                                                         \
    /* softmax numerator (no max: scores bounded ~O(3)), pack, publish */     \
    _Pragma("unroll") for (int jf = 0; jf < 8; jf++) {                        \
      float p0 = __expf(s[jf][0]); float p1 = __expf(s[jf][1]);               \
      float p2 = __expf(s[jf][2]); float p3 = __expf(s[jf][3]);               \
      lsum += p0 + p1 + p2 + p3;                                              \
      short4 pa; pa.x = f2bf(p0); pa.y = f2bf(p1);                            \
      pa.z = f2bf(p2); pa.w = f2bf(p3);                                       \
      const int u = (jf * 2 + (quad >> 1)) ^ swz;                             \
      *(short4*)&Plds[BUF][prowW + u * 8] = pa;                               \
    }                                                                         \
    /* publish P: wait LDS writes only; vmcnt stays in flight (T4) */         \
    asm volatile("s_waitcnt lgkmcnt(0)" ::: "memory");                        \
    __builtin_amdgcn_s_barrier();                                             \
    asm volatile("" ::: "memory");                                            \
    bf16x8 vf2[4];                                                            \
    _Pragma("unroll") for (int ct = 0; ct < 4; ct++)                          \
      vf2[ct] = *(const bf16x8*)(vb + 2 * SUBT + (ct*16+l16)*32 + quad*8);    \
    __builtin_amdgcn_s_setprio(1);                                            \
    /* PV ks0 */                                                              \
    _Pragma("unroll") for (int qt = 0; qt < 4; ++qt) {                        \
      const bf16x8 pf = *(const bf16x8*)                                      \
        &Plds[BUF][(qt*16+l16)*128 + ((0*4+quad)^swz)*8];                     \
      _Pragma("unroll") for (int ct = 0; ct < 4; ++ct)                        \
        acc[ct][qt] = __builtin_amdgcn_mfma_f32_16x16x32_bf16(                \
            vf0[ct], pf, acc[ct][qt], 0, 0, 0);                               \
    }                                                                         \
    bf16x8 vf3[4];                                                            \
    _Pragma("unroll") for (int ct = 0; ct < 4; ct++)                          \
      vf3[ct] = *(const bf16x8*)(vb + 3 * SUBT + (ct*16+l16)*32 + quad*8);    \
    /* PV ks1 */                                                              \
    _Pragma("unroll") for (int qt = 0; qt < 4; ++qt) {                        \
      const bf16x8 pf = *(const bf16x8*)                                      \
        &Plds[BUF][(qt*16+l16)*128 + ((1*4+quad)^swz)*8];                     \
      _Pragma("unroll") for (int ct = 0; ct < 4; ++ct)                        \
        acc[ct][qt] = __builtin_amdgcn_mfma_f32_16x16x32_bf16(                \
            vf1[ct], pf, acc[ct][qt], 0, 0, 0);                               \
    }                                                                         \
    /* PV ks2 */                                                              \
    _Pragma("unroll") for (int qt = 0; qt < 4; ++qt) {                        \
      const bf16x8 pf = *(const bf16x8*)                                      \
        &Plds[BUF][(qt*16+l16)*128 + ((2*4+quad)^swz)*8];                     \
      _Pragma("unroll") for (int ct = 0; ct < 4; ++ct)                        \
        acc[ct][qt] = __builtin_amdgcn_mfma_f32_16x16x32_bf16(                \
            vf2[ct], pf, acc[ct][qt], 0, 0, 0);                               \
    }                                                                         \
    /* PV ks3 */                                                              \
    _Pragma("unroll") for (int qt = 0; qt < 4; ++qt) {                        \
      const bf16x8 pf = *(const bf16x8*)                                      \
        &Plds[BUF][(qt*16+l16)*128 + ((3*4+quad)^swz)*8];                     \
      _Pragma("unroll") for (int ct = 0; ct < 4; ++ct)                        \
        acc[ct][qt] = __builtin_amdgcn_mfma_f32_16x16x32_bf16(                \
            vf3[ct], pf, acc[ct][qt], 0, 0, 0);                               \
    }                                                                         \
    __builtin_amdgcn_s_setprio(0);                                            \
  }

__global__ __launch_bounds__(256, 2) void attn_kernel(
    const short* __restrict__ qws, const short* __restrict__ kws,
    const short* __restrict__ vws,
    float* __restrict__ out, short* __restrict__ pnum1, float* __restrict__ pl)
{
    __shared__ short Plds[2][64 * 128];   // 2 x 16 KB

    const int blk = blockIdx.x;
    const int b   = blk & 3;
    const int js  = (blk >> 2) & 1;
    const int qc  = blk >> 3;            // 0..63
    const int t   = threadIdx.x;
    const int w   = t >> 6, lane = t & 63, l16 = lane & 15, quad = lane >> 4;
    const int q   = qc * 64 + w * 16 + l16;   // QK-duty q row for this lane

    const bf16x8 qf = *(const bf16x8*)&qws[((size_t)b * N_ + q) * C8_ + quad * 8];

    f32x4 acc[4][4];
    #pragma unroll
    for (int i = 0; i < 4; i++)
        #pragma unroll
        for (int j = 0; j < 4; j++) acc[i][j] = (f32x4){0.f, 0.f, 0.f, 0.f};
    float lsum = 0.f;

    const short* kbase = kws + ((size_t)b * N_ + js * NJ) * C8_;
    // tiled V: this wave's c-slice [64w, 64w+64) within each subtile
    const short* vbase = vws + ((size_t)((b * 2 + js) * 64)) * SUBT + w * 64 * 32;

    // swizzle: 16B unit u' = u ^ (row&7); row&7 == l16&7 for write row
    // (w*16+l16) and all read rows (qt*16+l16).
    const int swz   = l16 & 7;
    const int prowW = (w * 16 + l16) * 128 + (quad & 1) * 4;   // + u'*8

    // prologue: kf for tile 0 (8 j-frags x K=32), ping buffer
    bf16x8 kfA[8], kfB[8];
    #pragma unroll
    for (int jf = 0; jf < 8; jf++)
        kfA[jf] = *(const bf16x8*)(kbase + (size_t)(jf * 16 + l16) * C8_ + quad * 8);

    #pragma unroll 1
    for (int tile = 0; tile < NT2; tile += 2) {
        TILE_BODY(tile,     kfA, kfB, 0);
        TILE_BODY(tile + 1, kfB, kfA, 1);
    }

    // denominator partial for this wave's q over its full j half
    lsum += __shfl_xor(lsum, 16, 64);
    lsum += __shfl_xor(lsum, 32, 64);
    if (quad == 0) pl[(size_t)js * 16384 + (size_t)b * N_ + q] = lsum;

    // numerator partial: js0 -> fp32 into out, js1 -> bf16 into pnum1
    const int qq = qc * 64 + l16;
    if (js == 0) {
        float* ob = out + (size_t)b * C_ * N_;
        #pragma unroll
        for (int ct = 0; ct < 4; ++ct)
            #pragma unroll
            for (int qt = 0; qt < 4; ++qt)
                #pragma unroll
                for (int r = 0; r < 4; ++r) {
                    const int c = w * 64 + ct * 16 + quad * 4 + r;
                    ob[(size_t)c * N_ + qq + qt * 16] = acc[ct][qt][r];
                }
    } else {
        short* pb1 = pnum1 + (size_t)b * C_ * N_;
        #pragma unroll
        for (int ct = 0; ct < 4; ++ct)
            #pragma unroll
            for (int qt = 0; qt < 4; ++qt)
                #pragma unroll
                for (int r = 0; r < 4; ++r) {
                    const int c = w * 64 + ct * 16 + quad * 4 + r;
                    pb1[(size_t)c * N_ + qq + qt * 16] = f2bf(acc[ct][qt][r]);
                }
    }
}

// ---------------------------------------------------------------------------
// Kernel 3: linv = 1/(pl0+pl1).  Kernel 4: out = g*(out + pnum1)*linv + x.
// ---------------------------------------------------------------------------
__global__ __launch_bounds__(256) void lred_kernel(
    const float* __restrict__ pl, float* __restrict__ linv)
{
    const int i = blockIdx.x * 256 + threadIdx.x;   // over B*N = 16384
    linv[i] = 1.0f / (pl[i] + pl[16384 + i]);
}

__global__ __launch_bounds__(256) void combine_kernel(
    const short* __restrict__ pnum1, const float* __restrict__ linv,
    const float* __restrict__ x, const float* __restrict__ gamma,
    float* __restrict__ out)
{
    const size_t i4 = ((size_t)blockIdx.x * 256 + threadIdx.x) * 4;   // < BCN
    const float4 nv = *(const float4*)(out + i4);
    const short4 n1 = *(const short4*)(pnum1 + i4);
    const float4 xv = *(const float4*)(x + i4);
    const int   bn  = (int)((i4 >> 20) * 4096 + (i4 & 4095));         // b*N + n
    const float4 lv = *(const float4*)(linv + bn);
    const float g0 = gamma[0];
    float4 o;
    o.x = g0 * ((nv.x + bf2f(n1.x)) * lv.x) + xv.x;
    o.y = g0 * ((nv.y + bf2f(n1.y)) * lv.y) + xv.y;
    o.z = g0 * ((nv.z + bf2f(n1.z)) * lv.z) + xv.z;
    o.w = g0 * ((nv.w + bf2f(n1.w)) * lv.w) + xv.w;
    *(float4*)(out + i4) = o;
}

extern "C" void kernel_launch(void* const* d_in, const int* in_sizes, int n_in,
                              void* d_out, int out_size, void* d_ws, size_t ws_size,
                              hipStream_t stream)
{
    const float* x     = (const float*)d_in[0];
    const float* Wq    = (const float*)d_in[1];
    const float* bq    = (const float*)d_in[2];
    const float* Wk    = (const float*)d_in[3];
    const float* bk    = (const float*)d_in[4];
    const float* Wv    = (const float*)d_in[5];
    const float* bv    = (const float*)d_in[6];
    const float* gamma = (const float*)d_in[7];
    float* out = (float*)d_out;

    // ws layout, 18.4 MiB total (proven-safe).
    // pnum1 overlaps xT: xT dead after proj_kernel, pnum1 written by attn.
    char* base = (char*)d_ws;
    short* vws   = (short*)(base);                      // 8 MB  [8][64][256][32] tiled
    short* qws   = (short*)(base + 0x800000);           // 1 MB  [B][N][32]
    short* kws   = (short*)(base + 0x900000);           // 1 MB  [B][N][32]
    float* pl    = (float*)(base + 0xA00000);           // 128 KB [2][B*N]
    float* linv  = (float*)(base + 0xA20000);           // 64 KB
    short* Wall  = (short*)(base + 0xA30000);           // 160 KB
    float* ball  = (float*)(base + 0xA58000);           // 1.25 KB
    short* xT    = (short*)(base + 0xA60000);           // 8 MB  [B][N][256]
    short* pnum1 = (short*)(base + 0xA60000);           // 8 MB  [B][256][N] (over xT)

    prep_kernel<<<1065, 256, 0, stream>>>(x, Wq, bq, Wk, bk, Wv, bv, xT, Wall, ball);
    proj_kernel<<<dim3(N_ / 64, 2, B_), 256, 0, stream>>>(xT, Wall, ball, qws, kws, vws);
    attn_kernel<<<512, 256, 0, stream>>>(qws, kws, vws, out, pnum1, pl);
    lred_kernel<<<64, 256, 0, stream>>>(pl, linv);
    combine_kernel<<<4096, 256, 0, stream>>>(pnum1, linv, x, gamma, out);
}

// Round 8
// 164.736 us; speedup vs baseline: 2.1754x; 1.0116x over previous
//
#include <hip/hip_runtime.h>

#define B_   4
#define C_   256
#define C8_  32
#define N_   4096
#define JS   2                 // key split: js0 -> fp32 in d_out, js1 -> bf16 pnum1
#define NJ   (N_ / JS)         // 2048 keys per attn block
#define KB2  128               // j per tile
#define NT2  (NJ / KB2)        // 16 j-tiles per attn block
#define SUBT 8192              // shorts per V subtile: 256 c x 32 j
#define BCN  ((size_t)B_ * C_ * N_)   // 4,194,304

typedef __attribute__((ext_vector_type(8))) short bf16x8;
typedef __attribute__((ext_vector_type(4))) float f32x4;

__device__ inline short f2bf(float f) {
    union { float f; unsigned u; } v; v.f = f;
    unsigned r = v.u + 0x7FFFu + ((v.u >> 16) & 1u);   // RNE
    return (short)(r >> 16);
}
__device__ inline float bf2f(short s) {
    union { unsigned u; float f; } v; v.u = ((unsigned)(unsigned short)s) << 16;
    return v.f;
}

// ---------------------------------------------------------------------------
// Kernel 0: prep, v9. blocks [0,1024): transpose x -> FRAGMENT-PACKED xT:
// element (b, n, c) at [((b*256 + n/16)*8 + c/32)*512 + (quad*16+l16)*8 + j]
// with quad=(c%32)/8, l16=n%15... n%16, j=c%8 -- i.e. exactly the per-lane
// MFMA A-operand order proj consumes, so proj's bfr loads are contiguous 1KB.
// Write phase: each wave stores ONE contiguous 1KB fragment per pass (2
// passes) -- no scattered segments (the v8 scatter-tax lesson applied).
// blocks [1024,1064): W fp32 -> fragment-packed Wall[((gct*8+k)*64+lane)*8+j].
// block 1064: bias gather ball[320].
// ---------------------------------------------------------------------------
__global__ __launch_bounds__(256) void prep_kernel(
    const float* __restrict__ x,
    const float* __restrict__ Wq, const float* __restrict__ bq,
    const float* __restrict__ Wk, const float* __restrict__ bk,
    const float* __restrict__ Wv, const float* __restrict__ bv,
    short* __restrict__ xT, short* __restrict__ Wall, float* __restrict__ ball)
{
    const int blk = blockIdx.x;
    const int t   = threadIdx.x;
    if (blk < 1024) {
        __shared__ float tile[64 * 67];
        const int b   = blk >> 8;
        const int rem = blk & 255;
        const int c0  = (rem >> 6) << 6;
        const int n0  = (rem & 63) << 6;
        const float* xb = x + ((size_t)b * C_ + c0) * N_ + n0;
        #pragma unroll
        for (int i = 0; i < 4; i++) {
            int e = t + i * 256;                 // 1024 float4 = 64 rows x 16
            int c = e >> 4, n4 = (e & 15) * 4;
            float4 v = *(const float4*)(xb + (size_t)c * N_ + n4);
            float* dst = &tile[c * 67 + n4];
            dst[0] = v.x; dst[1] = v.y; dst[2] = v.z; dst[3] = v.w;
        }
        __syncthreads();
        // fragment-packed write: pass p, wave w -> fragment fid = p*4 + w
        // (g = fid>>1 in 0..3, k = fid&1); lane writes shorts [lane*8, +8).
        const int G0 = n0 >> 4;                  // first of 4 n-groups
        const int K0 = c0 >> 5;                  // first of 2 k (c/32) groups
        #pragma unroll
        for (int pass = 0; pass < 2; pass++) {
            const int f    = pass * 2048 + t * 8;    // 0..4095
            const int fid  = f >> 9;                 // 0..7
            const int g    = fid >> 1, k = fid & 1;
            const int lane = (f >> 3) & 63;
            const int quad = lane >> 4, l16 = lane & 15;
            // 8 shorts: c_local = k*32 + quad*8 + j, n_local = g*16 + l16
            const float* tc = &tile[(k * 32 + quad * 8) * 67 + g * 16 + l16];
            short4 s0, s1;
            s0.x = f2bf(tc[0 * 67]); s0.y = f2bf(tc[1 * 67]);
            s0.z = f2bf(tc[2 * 67]); s0.w = f2bf(tc[3 * 67]);
            s1.x = f2bf(tc[4 * 67]); s1.y = f2bf(tc[5 * 67]);
            s1.z = f2bf(tc[6 * 67]); s1.w = f2bf(tc[7 * 67]);
            short* d = xT + ((size_t)(b * 256 + G0 + g) * 8 + (K0 + k)) * 512
                          + lane * 8;
            *(short4*)d       = s0;
            *(short4*)(d + 4) = s1;
        }
    } else if (blk < 1064) {
        const int base = (blk - 1024) * 2048 + t * 8;   // 40*2048 = 320*256
        const int r = base >> 8, cc = base & 255;       // cc is 8-aligned
        const float* src = (r < 32) ? &Wq[r * C_ + cc]
                         : (r < 64) ? &Wk[(r - 32) * C_ + cc]
                                    : &Wv[(r - 64) * C_ + cc];
        const float4 a  = *(const float4*)src;
        const float4 b4 = *(const float4*)(src + 4);
        short4 s1, s2;
        s1.x = f2bf(a.x);  s1.y = f2bf(a.y);  s1.z = f2bf(a.z);  s1.w = f2bf(a.w);
        s2.x = f2bf(b4.x); s2.y = f2bf(b4.y); s2.z = f2bf(b4.z); s2.w = f2bf(b4.w);
        // fragment-packed dest: gct = r>>4, l16 = r&15, k = cc>>5, quad = (cc>>3)&3
        {
            const int gct = r >> 4, l16w = r & 15;
            const int k   = cc >> 5, quad = (cc >> 3) & 3;
            short* d = &Wall[(((size_t)(gct * 8 + k) * 4 + quad) * 16 + l16w) * 8];
            *(short4*)d       = s1;
            *(short4*)(d + 4) = s2;
        }
    } else {
        for (int i = t; i < 320; i += 256)
            ball[i] = (i < 32) ? bq[i] : (i < 64) ? bk[i - 32] : bv[i - 64];
    }
}

// ---------------------------------------------------------------------------
// Kernel 1: MFMA projections, v9. Same math as v8; the 88 scattered loads
// per wave (af: 512B-stride rows; bfr: per-lane n rows) are now contiguous
// 1KB fragment loads from the packed Wall/xT (scatter-tax fix, the lever
// validated by v8's attn win). V written tile-contiguous as in v8.
// ---------------------------------------------------------------------------
__global__ __launch_bounds__(256, 2) void proj_kernel(
    const short* __restrict__ xT, const short* __restrict__ Wall,
    const float* __restrict__ ball,
    short* __restrict__ qws, short* __restrict__ kws, short* __restrict__ vws)
{
    const int n0    = blockIdx.x * 64;
    const int split = blockIdx.y;
    const int b     = blockIdx.z;
    const int t     = threadIdx.x;
    const int w     = t >> 6, lane = t & 63, l16 = lane & 15, quad = lane >> 4;
    const int n     = n0 + w * 16 + l16;

    // bfr: 8 contiguous 1KB fragment loads (n-group = n0/16 + w)
    bf16x8 bfr[8];
    const short* xf = xT + ((size_t)(b * 256 + blockIdx.x * 4 + w) * 8) * 512
                         + lane * 8;
    #pragma unroll
    for (int k = 0; k < 8; k++) bfr[k] = *(const bf16x8*)(xf + k * 512);

    f32x4 acc[10];
    #pragma unroll
    for (int i = 0; i < 10; i++) acc[i] = (f32x4){0.f, 0.f, 0.f, 0.f};

    const int gct0 = split * 10;
    #pragma unroll
    for (int k = 0; k < 8; k++) {
        #pragma unroll
        for (int ct = 0; ct < 10; ct++) {
            const bf16x8 af = *(const bf16x8*)
                &Wall[(size_t)((gct0 + ct) * 8 + k) * 512 + lane * 8];
            acc[ct] = __builtin_amdgcn_mfma_f32_16x16x32_bf16(af, bfr[k], acc[ct], 0, 0, 0);
        }
    }

    // V destination: tiled layout [b*2+js][sub][c][j] (v8, attn-contiguous)
    const int js  = n >> 11;            // n / 2048
    const int sub = (n >> 5) & 63;      // 32-j subtile within the js half
    const int jj  = n & 31;
    short* vdst = vws + ((size_t)((b * 2 + js) * 64 + sub)) * SUBT + jj;

    #pragma unroll
    for (int ct = 0; ct < 10; ct++) {
        const int gct = gct0 + ct;
        const int cb  = gct * 16 + quad * 4;
        float v0 = acc[ct][0] + ball[cb + 0];
        float v1 = acc[ct][1] + ball[cb + 1];
        float v2 = acc[ct][2] + ball[cb + 2];
        float v3 = acc[ct][3] + ball[cb + 3];
        if (gct < 2) {
            short4 s; s.x = f2bf(v0); s.y = f2bf(v1); s.z = f2bf(v2); s.w = f2bf(v3);
            *(short4*)&qws[((size_t)b * N_ + n) * C8_ + cb] = s;
        } else if (gct < 4) {
            short4 s; s.x = f2bf(v0); s.y = f2bf(v1); s.z = f2bf(v2); s.w = f2bf(v3);
            *(short4*)&kws[((size_t)b * N_ + n) * C8_ + (cb - 32)] = s;
        } else {
            const int c = cb - 64;
            vdst[(c + 0) * 32] = f2bf(v0);
            vdst[(c + 1) * 32] = f2bf(v1);
            vdst[(c + 2) * 32] = f2bf(v2);
            vdst[(c + 3) * 32] = f2bf(v3);
        }
    }
}

// ---------------------------------------------------------------------------
// Kernel 2: MFMA flash attention -- BYTE-IDENTICAL to the benched v8 (58.4us,
// MfmaUtil 26.6%): serves as this round's A/B control. Tile-contiguous V
// fixed the TA segment-service wall (+32%).
// ---------------------------------------------------------------------------
#define TILE_BODY(TILE, KC, KN, BUF)                                          \
  {                                                                           \
    const short* vb = vbase + (size_t)(TILE) * 4 * SUBT;                      \
    /* V ks0/ks1: issue early (covered by QK+exp+pack; no drain at barrier)*/ \
    bf16x8 vf0[4], vf1[4];                                                    \
    _Pragma("unroll") for (int ct = 0; ct < 4; ct++)                          \
      vf0[ct] = *(const bf16x8*)(vb + 0 * SUBT + (ct*16+l16)*32 + quad*8);    \
    _Pragma("unroll") for (int ct = 0; ct < 4; ct++)                          \
      vf1[ct] = *(const bf16x8*)(vb + 1 * SUBT + (ct*16+l16)*32 + quad*8);    \
    /* QK^T: S^T[j][q] for this wave's 16 q over 128 j */                     \
    f32x4 s[8];                                                               \
    _Pragma("unroll") for (int jf = 0; jf < 8; jf++)                          \
      s[jf] = __builtin_amdgcn_mfma_f32_16x16x32_bf16(KC[jf], qf,             \
              (f32x4){0.f,0.f,0.f,0.f}, 0, 0, 0);                             \
    /* K prefetch for next tile into the other buffer (clamped, branchless)*/ \
    {                                                                         \
      const int tn = ((TILE) + 1 < NT2) ? (TILE) + 1 : (TILE);                \
      const short* kb = kbase + (size_t)(tn * KB2) * C8_;                     \
      _Pragma("unroll") for (int jf = 0; jf < 8; jf++)                        \
        KN[jf] = *(const bf16x8*)(kb + (size_t)(jf*16+l16)*C8_ + quad*8);     \
    }                                                                         \
    /* softmax numerator (no max: scores bounded ~O(3)), pack, publish */     \
    _Pragma("unroll") for (int jf = 0; jf < 8; jf++) {                        \
      float p0 = __expf(s[jf][0]); float p1 = __expf(s[jf][1]);               \
      float p2 = __expf(s[jf][2]); float p3 = __expf(s[jf][3]);               \
      lsum += p0 + p1 + p2 + p3;                                              \
      short4 pa; pa.x = f2bf(p0); pa.y = f2bf(p1);                            \
      pa.z = f2bf(p2); pa.w = f2bf(p3);                                       \
      const int u = (jf * 2 + (quad >> 1)) ^ swz;                             \
      *(short4*)&Plds[BUF][prowW + u * 8] = pa;                               \
    }                                                                         \
    /* publish P: wait LDS writes only; vmcnt stays in flight (T4) */         \
    asm volatile("s_waitcnt lgkmcnt(0)" ::: "memory");                        \
    __builtin_amdgcn_s_barrier();                                             \
    asm volatile("" ::: "memory");                                            \
    bf16x8 vf2[4];                                                            \
    _Pragma("unroll") for (int ct = 0; ct < 4; ct++)                          \
      vf2[ct] = *(const bf16x8*)(vb + 2 * SUBT + (ct*16+l16)*32 + quad*8);    \
    __builtin_amdgcn_s_setprio(1);                                            \
    /* PV ks0 */                                                              \
    _Pragma("unroll") for (int qt = 0; qt < 4; ++qt) {                        \
      const bf16x8 pf = *(const bf16x8*)                                      \
        &Plds[BUF][(qt*16+l16)*128 + ((0*4+quad)^swz)*8];                     \
      _Pragma("unroll") for (int ct = 0; ct < 4; ++ct)                        \
        acc[ct][qt] = __builtin_amdgcn_mfma_f32_16x16x32_bf16(                \
            vf0[ct], pf, acc[ct][qt], 0, 0, 0);                               \
    }                                                                         \
    bf16x8 vf3[4];                                                            \
    _Pragma("unroll") for (int ct = 0; ct < 4; ct++)                          \
      vf3[ct] = *(const bf16x8*)(vb + 3 * SUBT + (ct*16+l16)*32 + quad*8);    \
    /* PV ks1 */                                                              \
    _Pragma("unroll") for (int qt = 0; qt < 4; ++qt) {                        \
      const bf16x8 pf = *(const bf16x8*)                                      \
        &Plds[BUF][(qt*16+l16)*128 + ((1*4+quad)^swz)*8];                     \
      _Pragma("unroll") for (int ct = 0; ct < 4; ++ct)                        \
        acc[ct][qt] = __builtin_amdgcn_mfma_f32_16x16x32_bf16(                \
            vf1[ct], pf, acc[ct][qt], 0, 0, 0);                               \
    }                                                                         \
    /* PV ks2 */                                                              \
    _Pragma("unroll") for (int qt = 0; qt < 4; ++qt) {                        \
      const bf16x8 pf = *(const bf16x8*)                                      \
        &Plds[BUF][(qt*16+l16)*128 + ((2*4+quad)^swz)*8];                     \
      _Pragma("unroll") for (int ct = 0; ct < 4; ++ct)                        \
        acc[ct][qt] = __builtin_amdgcn_mfma_f32_16x16x32_bf16(                \
            vf2[ct], pf, acc[ct][qt], 0, 0, 0);                               \
    }                                                                         \
    /* PV ks3 */                                                              \
    _Pragma("unroll") for (int qt = 0; qt < 4; ++qt) {                        \
      const bf16x8 pf = *(const bf16x8*)                                      \
        &Plds[BUF][(qt*16+l16)*128 + ((3*4+quad)^swz)*8];                     \
      _Pragma("unroll") for (int ct = 0; ct < 4; ++ct)                        \
        acc[ct][qt] = __builtin_amdgcn_mfma_f32_16x16x32_bf16(                \
            vf3[ct], pf, acc[ct][qt], 0, 0, 0);                               \
    }                                                                         \
    __builtin_amdgcn_s_setprio(0);                                            \
  }

__global__ __launch_bounds__(256, 2) void attn_kernel(
    const short* __restrict__ qws, const short* __restrict__ kws,
    const short* __restrict__ vws,
    float* __restrict__ out, short* __restrict__ pnum1, float* __restrict__ pl)
{
    __shared__ short Plds[2][64 * 128];   // 2 x 16 KB

    const int blk = blockIdx.x;
    const int b   = blk & 3;
    const int js  = (blk >> 2) & 1;
    const int qc  = blk >> 3;            // 0..63
    const int t   = threadIdx.x;
    const int w   = t >> 6, lane = t & 63, l16 = lane & 15, quad = lane >> 4;
    const int q   = qc * 64 + w * 16 + l16;   // QK-duty q row for this lane

    const bf16x8 qf = *(const bf16x8*)&qws[((size_t)b * N_ + q) * C8_ + quad * 8];

    f32x4 acc[4][4];
    #pragma unroll
    for (int i = 0; i < 4; i++)
        #pragma unroll
        for (int j = 0; j < 4; j++) acc[i][j] = (f32x4){0.f, 0.f, 0.f, 0.f};
    float lsum = 0.f;

    const short* kbase = kws + ((size_t)b * N_ + js * NJ) * C8_;
    // tiled V: this wave's c-slice [64w, 64w+64) within each subtile
    const short* vbase = vws + ((size_t)((b * 2 + js) * 64)) * SUBT + w * 64 * 32;

    // swizzle: 16B unit u' = u ^ (row&7); row&7 == l16&7 for write row
    // (w*16+l16) and all read rows (qt*16+l16).
    const int swz   = l16 & 7;
    const int prowW = (w * 16 + l16) * 128 + (quad & 1) * 4;   // + u'*8

    // prologue: kf for tile 0 (8 j-frags x K=32), ping buffer
    bf16x8 kfA[8], kfB[8];
    #pragma unroll
    for (int jf = 0; jf < 8; jf++)
        kfA[jf] = *(const bf16x8*)(kbase + (size_t)(jf * 16 + l16) * C8_ + quad * 8);

    #pragma unroll 1
    for (int tile = 0; tile < NT2; tile += 2) {
        TILE_BODY(tile,     kfA, kfB, 0);
        TILE_BODY(tile + 1, kfB, kfA, 1);
    }

    // denominator partial for this wave's q over its full j half
    lsum += __shfl_xor(lsum, 16, 64);
    lsum += __shfl_xor(lsum, 32, 64);
    if (quad == 0) pl[(size_t)js * 16384 + (size_t)b * N_ + q] = lsum;

    // numerator partial: js0 -> fp32 into out, js1 -> bf16 into pnum1
    const int qq = qc * 64 + l16;
    if (js == 0) {
        float* ob = out + (size_t)b * C_ * N_;
        #pragma unroll
        for (int ct = 0; ct < 4; ++ct)
            #pragma unroll
            for (int qt = 0; qt < 4; ++qt)
                #pragma unroll
                for (int r = 0; r < 4; ++r) {
                    const int c = w * 64 + ct * 16 + quad * 4 + r;
                    ob[(size_t)c * N_ + qq + qt * 16] = acc[ct][qt][r];
                }
    } else {
        short* pb1 = pnum1 + (size_t)b * C_ * N_;
        #pragma unroll
        for (int ct = 0; ct < 4; ++ct)
            #pragma unroll
            for (int qt = 0; qt < 4; ++qt)
                #pragma unroll
                for (int r = 0; r < 4; ++r) {
                    const int c = w * 64 + ct * 16 + quad * 4 + r;
                    pb1[(size_t)c * N_ + qq + qt * 16] = f2bf(acc[ct][qt][r]);
                }
    }
}

// ---------------------------------------------------------------------------
// Kernel 3: combine with lred FUSED: linv computed inline as 1.0f/(pl0+pl1)
// (identical expression/rounding to the old lred), saving one launch.
// out = g*(out + pnum1)*linv + x.
// ---------------------------------------------------------------------------
__global__ __launch_bounds__(256) void combine_kernel(
    const short* __restrict__ pnum1, const float* __restrict__ pl,
    const float* __restrict__ x, const float* __restrict__ gamma,
    float* __restrict__ out)
{
    const size_t i4 = ((size_t)blockIdx.x * 256 + threadIdx.x) * 4;   // < BCN
    const float4 nv = *(const float4*)(out + i4);
    const short4 n1 = *(const short4*)(pnum1 + i4);
    const float4 xv = *(const float4*)(x + i4);
    const int   bn  = (int)((i4 >> 20) * 4096 + (i4 & 4095));         // b*N + n
    const float4 p0 = *(const float4*)(pl + bn);
    const float4 p1 = *(const float4*)(pl + 16384 + bn);
    float4 lv;
    lv.x = 1.0f / (p0.x + p1.x);
    lv.y = 1.0f / (p0.y + p1.y);
    lv.z = 1.0f / (p0.z + p1.z);
    lv.w = 1.0f / (p0.w + p1.w);
    const float g0 = gamma[0];
    float4 o;
    o.x = g0 * ((nv.x + bf2f(n1.x)) * lv.x) + xv.x;
    o.y = g0 * ((nv.y + bf2f(n1.y)) * lv.y) + xv.y;
    o.z = g0 * ((nv.z + bf2f(n1.z)) * lv.z) + xv.z;
    o.w = g0 * ((nv.w + bf2f(n1.w)) * lv.w) + xv.w;
    *(float4*)(out + i4) = o;
}

extern "C" void kernel_launch(void* const* d_in, const int* in_sizes, int n_in,
                              void* d_out, int out_size, void* d_ws, size_t ws_size,
                              hipStream_t stream)
{
    const float* x     = (const float*)d_in[0];
    const float* Wq    = (const float*)d_in[1];
    const float* bq    = (const float*)d_in[2];
    const float* Wk    = (const float*)d_in[3];
    const float* bk    = (const float*)d_in[4];
    const float* Wv    = (const float*)d_in[5];
    const float* bv    = (const float*)d_in[6];
    const float* gamma = (const float*)d_in[7];
    float* out = (float*)d_out;

    // ws layout, 18.4 MiB total (proven-safe).
    // pnum1 overlaps xT: xT dead after proj_kernel, pnum1 written by attn.
    char* base = (char*)d_ws;
    short* vws   = (short*)(base);                      // 8 MB  [8][64][256][32] tiled
    short* qws   = (short*)(base + 0x800000);           // 1 MB  [B][N][32]
    short* kws   = (short*)(base + 0x900000);           // 1 MB  [B][N][32]
    float* pl    = (float*)(base + 0xA00000);           // 128 KB [2][B*N]
    short* Wall  = (short*)(base + 0xA30000);           // 160 KB fragment-packed
    float* ball  = (float*)(base + 0xA58000);           // 1.25 KB
    short* xT    = (short*)(base + 0xA60000);           // 8 MB  fragment-packed
    short* pnum1 = (short*)(base + 0xA60000);           // 8 MB  [B][256][N] (over xT)

    prep_kernel<<<1065, 256, 0, stream>>>(x, Wq, bq, Wk, bk, Wv, bv, xT, Wall, ball);
    proj_kernel<<<dim3(N_ / 64, 2, B_), 256, 0, stream>>>(xT, Wall, ball, qws, kws, vws);
    attn_kernel<<<512, 256, 0, stream>>>(qws, kws, vws, out, pnum1, pl);
    combine_kernel<<<4096, 256, 0, stream>>>(pnum1, pl, x, gamma, out);
}

// Round 9
// 144.266 us; speedup vs baseline: 2.4840x; 1.1419x over previous
//
#include <hip/hip_runtime.h>

#define B_   4
#define C_   256
#define C8_  32
#define N_   4096
#define JS   2                 // key split: js0 -> fp32 in d_out, js1 -> bf16 pnum1
#define NJ   (N_ / JS)         // 2048 keys per attn block
#define KB2  128               // j per tile
#define NT2  (NJ / KB2)        // 16 j-tiles per attn block
#define SUBT 8192              // shorts per V subtile: 256 c x 32 j
#define BCN  ((size_t)B_ * C_ * N_)   // 4,194,304

typedef __attribute__((ext_vector_type(8))) short bf16x8;
typedef __attribute__((ext_vector_type(4))) float f32x4;

__device__ inline short f2bf(float f) {
    union { float f; unsigned u; } v; v.f = f;
    unsigned r = v.u + 0x7FFFu + ((v.u >> 16) & 1u);   // RNE
    return (short)(r >> 16);
}
__device__ inline float bf2f(short s) {
    union { unsigned u; float f; } v; v.u = ((unsigned)(unsigned short)s) << 16;
    return v.f;
}

// ---------------------------------------------------------------------------
// Kernel 0: prep, v10 (tiny). blocks [0,40): W fp32 -> fragment-packed
// Wall[((gct*8+k)*4+quad)*16+l16)*8 + j] (one contiguous wave-store each).
// block 40: bias gather ball[320]. The x-transpose moved INTO proj (xT gone).
// ---------------------------------------------------------------------------
__global__ __launch_bounds__(256) void prep_kernel(
    const float* __restrict__ Wq, const float* __restrict__ bq,
    const float* __restrict__ Wk, const float* __restrict__ bk,
    const float* __restrict__ Wv, const float* __restrict__ bv,
    short* __restrict__ Wall, float* __restrict__ ball)
{
    const int blk = blockIdx.x;
    const int t   = threadIdx.x;
    if (blk < 40) {
        const int base = blk * 2048 + t * 8;            // 40*2048 = 320*256
        const int r = base >> 8, cc = base & 255;       // cc is 8-aligned
        const float* src = (r < 32) ? &Wq[r * C_ + cc]
                         : (r < 64) ? &Wk[(r - 32) * C_ + cc]
                                    : &Wv[(r - 64) * C_ + cc];
        const float4 a  = *(const float4*)src;
        const float4 b4 = *(const float4*)(src + 4);
        short4 s1, s2;
        s1.x = f2bf(a.x);  s1.y = f2bf(a.y);  s1.z = f2bf(a.z);  s1.w = f2bf(a.w);
        s2.x = f2bf(b4.x); s2.y = f2bf(b4.y); s2.z = f2bf(b4.z); s2.w = f2bf(b4.w);
        const int gct = r >> 4, l16w = r & 15;
        const int k   = cc >> 5, quad = (cc >> 3) & 3;
        short* d = &Wall[(((size_t)(gct * 8 + k) * 4 + quad) * 16 + l16w) * 8];
        *(short4*)d       = s1;
        *(short4*)(d + 4) = s2;
    } else {
        for (int i = t; i < 320; i += 256)
            ball[i] = (i < 32) ? bq[i] : (i < 64) ? bk[i - 32] : bv[i - 64];
    }
}

// ---------------------------------------------------------------------------
// Kernel 1: FUSED transpose + MFMA projections, v10. Grid (N/64, B), 256 thr.
// Phase 1: stage x[b][0..255][n0..n0+63] -> bf16 LDS tile[256][68] (pad 68:
//   8B-aligned short4 writes; phase-2 reads are <=2-way bank = free).
// Phase 2: each wave builds its 8 bfr fragments from LDS (n = n0+w*16+l16),
//   then runs ALL 20 co-tiles x 8 k-steps (splits merged: halves Wall
//   re-reads and reads x ONCE -- kills the xT round-trip and a launch).
// Stores: q/k -> fragment-packed qws/kws [b][grp=n>>4][512] (contiguous
//   512B wave-stores; makes attn's K loads contiguous -- the R7-validated
//   segment-tax lever applied to K). v -> tiled vws as in v8/v9.
// Values bit-identical to v9 (same f2bf(x), same MFMA chain order).
// ---------------------------------------------------------------------------
__global__ __launch_bounds__(256) void proj_kernel(
    const float* __restrict__ x, const short* __restrict__ Wall,
    const float* __restrict__ ball,
    short* __restrict__ qws, short* __restrict__ kws, short* __restrict__ vws)
{
    __shared__ short tilebf[256 * 68];   // 34.8 KB

    const int n0 = blockIdx.x * 64;
    const int b  = blockIdx.y;
    const int t  = threadIdx.x;
    const int w  = t >> 6, lane = t & 63, l16 = lane & 15, quad = lane >> 4;

    // phase 1: x (fp32) -> bf16 LDS tile [c][nl], 16 float4 per thread
    const float* xb = x + (size_t)b * C_ * N_ + n0;
    #pragma unroll
    for (int i = 0; i < 16; i++) {
        int e = t + i * 256;                 // 4096 float4 = 256 rows x 16
        int c = e >> 4, n4 = (e & 15) * 4;
        float4 v = *(const float4*)(xb + (size_t)c * N_ + n4);
        short4 s;
        s.x = f2bf(v.x); s.y = f2bf(v.y); s.z = f2bf(v.z); s.w = f2bf(v.w);
        *(short4*)&tilebf[c * 68 + n4] = s;
    }
    __syncthreads();

    // phase 2: bfr fragments (n = n0 + w*16 + l16; c = k*32 + quad*8 + j)
    bf16x8 bfr[8];
    const int nl = w * 16 + l16;
    #pragma unroll
    for (int k = 0; k < 8; k++) {
        bf16x8 f;
        #pragma unroll
        for (int j = 0; j < 8; j++)
            f[j] = tilebf[(k * 32 + quad * 8 + j) * 68 + nl];
        bfr[k] = f;
    }

    f32x4 acc[20];
    #pragma unroll
    for (int i = 0; i < 20; i++) acc[i] = (f32x4){0.f, 0.f, 0.f, 0.f};

    #pragma unroll
    for (int k = 0; k < 8; k++) {
        #pragma unroll
        for (int ct = 0; ct < 20; ct++) {
            const bf16x8 af = *(const bf16x8*)
                &Wall[(size_t)(ct * 8 + k) * 512 + lane * 8];
            acc[ct] = __builtin_amdgcn_mfma_f32_16x16x32_bf16(af, bfr[k], acc[ct], 0, 0, 0);
        }
    }

    const int n   = n0 + w * 16 + l16;
    const int grp = (n0 >> 4) + w;          // = n>>4
    // V destination: tiled layout [b*2+js][sub][c][j]
    const int js  = n >> 11;
    const int sub = (n >> 5) & 63;
    const int jj  = n & 31;
    short* vdst = vws + ((size_t)((b * 2 + js) * 64 + sub)) * SUBT + jj;

    #pragma unroll
    for (int ct = 0; ct < 20; ct++) {
        const int cb = ct * 16 + quad * 4;
        float v0 = acc[ct][0] + ball[cb + 0];
        float v1 = acc[ct][1] + ball[cb + 1];
        float v2 = acc[ct][2] + ball[cb + 2];
        float v3 = acc[ct][3] + ball[cb + 3];
        if (ct < 2) {
            // q fragment-packed: [b][grp][ (ct*2+(quad>>1))*128 + l16*8 + (quad&1)*4 ]
            short4 s; s.x = f2bf(v0); s.y = f2bf(v1); s.z = f2bf(v2); s.w = f2bf(v3);
            *(short4*)&qws[((size_t)(b * 256 + grp)) * 512
                           + (ct * 2 + (quad >> 1)) * 128 + l16 * 8 + (quad & 1) * 4] = s;
        } else if (ct < 4) {
            short4 s; s.x = f2bf(v0); s.y = f2bf(v1); s.z = f2bf(v2); s.w = f2bf(v3);
            *(short4*)&kws[((size_t)(b * 256 + grp)) * 512
                           + ((ct - 2) * 2 + (quad >> 1)) * 128 + l16 * 8 + (quad & 1) * 4] = s;
        } else {
            const int c = (ct - 4) * 16 + quad * 4;
            vdst[(c + 0) * 32] = f2bf(v0);
            vdst[(c + 1) * 32] = f2bf(v1);
            vdst[(c + 2) * 32] = f2bf(v2);
            vdst[(c + 3) * 32] = f2bf(v3);
        }
    }
}

// ---------------------------------------------------------------------------
// Kernel 2: MFMA flash attention, v10 = v8/v9 structure with K and Q loads
// from the fragment-packed buffers: every per-tile K prefetch is 8 contiguous
// 1KB loads instead of 8 x 16-scattered-segment loads (the dominant remaining
// term in the closed per-period budget: ~4200 of 9700 cy). Values identical.
// ---------------------------------------------------------------------------
#define TILE_BODY(TILE, KC, KN, BUF)                                          \
  {                                                                           \
    const short* vb = vbase + (size_t)(TILE) * 4 * SUBT;                      \
    /* V ks0/ks1: issue early (covered by QK+exp+pack; no drain at barrier)*/ \
    bf16x8 vf0[4], vf1[4];                                                    \
    _Pragma("unroll") for (int ct = 0; ct < 4; ct++)                          \
      vf0[ct] = *(const bf16x8*)(vb + 0 * SUBT + (ct*16+l16)*32 + quad*8);    \
    _Pragma("unroll") for (int ct = 0; ct < 4; ct++)                          \
      vf1[ct] = *(const bf16x8*)(vb + 1 * SUBT + (ct*16+l16)*32 + quad*8);    \
    /* QK^T: S^T[j][q] for this wave's 16 q over 128 j */                     \
    f32x4 s[8];                                                               \
    _Pragma("unroll") for (int jf = 0; jf < 8; jf++)                          \
      s[jf] = __builtin_amdgcn_mfma_f32_16x16x32_bf16(KC[jf], qf,             \
              (f32x4){0.f,0.f,0.f,0.f}, 0, 0, 0);                             \
    /* K prefetch for next tile (contiguous 1KB fragment loads) */            \
    {                                                                         \
      const int tn = ((TILE) + 1 < NT2) ? (TILE) + 1 : (TILE);                \
      const short* kb = kfb + (size_t)(tn * 8) * 512;                         \
      _Pragma("unroll") for (int jf = 0; jf < 8; jf++)                        \
        KN[jf] = *(const bf16x8*)(kb + (size_t)jf * 512 + lane * 8);          \
    }                                                                         \
    /* softmax numerator (no max: scores bounded ~O(3)), pack, publish */     \
    _Pragma("unroll") for (int jf = 0; jf < 8; jf++) {                        \
      float p0 = __expf(s[jf][0]); float p1 = __expf(s[jf][1]);               \
      float p2 = __expf(s[jf][2]); float p3 = __expf(s[jf][3]);               \
      lsum += p0 + p1 + p2 + p3;                                              \
      short4 pa; pa.x = f2bf(p0); pa.y = f2bf(p1);                            \
      pa.z = f2bf(p2); pa.w = f2bf(p3);                                       \
      const int u = (jf * 2 + (quad >> 1)) ^ swz;                             \
      *(short4*)&Plds[BUF][prowW + u * 8] = pa;                               \
    }                                                                         \
    /* publish P: wait LDS writes only; vmcnt stays in flight (T4) */         \
    asm volatile("s_waitcnt lgkmcnt(0)" ::: "memory");                        \
    __builtin_amdgcn_s_barrier();                                             \
    asm volatile("" ::: "memory");                                            \
    bf16x8 vf2[4];                                                            \
    _Pragma("unroll") for (int ct = 0; ct < 4; ct++)                          \
      vf2[ct] = *(const bf16x8*)(vb + 2 * SUBT + (ct*16+l16)*32 + quad*8);    \
    __builtin_amdgcn_s_setprio(1);                                            \
    /* PV ks0 */                                                              \
    _Pragma("unroll") for (int qt = 0; qt < 4; ++qt) {                        \
      const bf16x8 pf = *(const bf16x8*)                                      \
        &Plds[BUF][(qt*16+l16)*128 + ((0*4+quad)^swz)*8];                     \
      _Pragma("unroll") for (int ct = 0; ct < 4; ++ct)                        \
        acc[ct][qt] = __builtin_amdgcn_mfma_f32_16x16x32_bf16(                \
            vf0[ct], pf, acc[ct][qt], 0, 0, 0);                               \
    }                                                                         \
    bf16x8 vf3[4];                                                            \
    _Pragma("unroll") for (int ct = 0; ct < 4; ct++)                          \
      vf3[ct] = *(const bf16x8*)(vb + 3 * SUBT + (ct*16+l16)*32 + quad*8);    \
    /* PV ks1 */                                                              \
    _Pragma("unroll") for (int qt = 0; qt < 4; ++qt) {                        \
      const bf16x8 pf = *(const bf16x8*)                                      \
        &Plds[BUF][(qt*16+l16)*128 + ((1*4+quad)^swz)*8];                     \
      _Pragma("unroll") for (int ct = 0; ct < 4; ++ct)                        \
        acc[ct][qt] = __builtin_amdgcn_mfma_f32_16x16x32_bf16(                \
            vf1[ct], pf, acc[ct][qt], 0, 0, 0);                               \
    }                                                                         \
    /* PV ks2 */                                                              \
    _Pragma("unroll") for (int qt = 0; qt < 4; ++qt) {                        \
      const bf16x8 pf = *(const bf16x8*)                                      \
        &Plds[BUF][(qt*16+l16)*128 + ((2*4+quad)^swz)*8];                     \
      _Pragma("unroll") for (int ct = 0; ct < 4; ++ct)                        \
        acc[ct][qt] = __builtin_amdgcn_mfma_f32_16x16x32_bf16(                \
            vf2[ct], pf, acc[ct][qt], 0, 0, 0);                               \
    }                                                                         \
    /* PV ks3 */                                                              \
    _Pragma("unroll") for (int qt = 0; qt < 4; ++qt) {                        \
      const bf16x8 pf = *(const bf16x8*)                                      \
        &Plds[BUF][(qt*16+l16)*128 + ((3*4+quad)^swz)*8];                     \
      _Pragma("unroll") for (int ct = 0; ct < 4; ++ct)                        \
        acc[ct][qt] = __builtin_amdgcn_mfma_f32_16x16x32_bf16(                \
            vf3[ct], pf, acc[ct][qt], 0, 0, 0);                               \
    }                                                                         \
    __builtin_amdgcn_s_setprio(0);                                            \
  }

__global__ __launch_bounds__(256, 2) void attn_kernel(
    const short* __restrict__ qws, const short* __restrict__ kws,
    const short* __restrict__ vws,
    float* __restrict__ out, short* __restrict__ pnum1, float* __restrict__ pl)
{
    __shared__ short Plds[2][64 * 128];   // 2 x 16 KB

    const int blk = blockIdx.x;
    const int b   = blk & 3;
    const int js  = (blk >> 2) & 1;
    const int qc  = blk >> 3;            // 0..63
    const int t   = threadIdx.x;
    const int w   = t >> 6, lane = t & 63, l16 = lane & 15, quad = lane >> 4;
    const int q   = qc * 64 + w * 16 + l16;   // QK-duty q row for this lane

    // Q from fragment-packed qws: group qc*4+w, contiguous 1KB per wave
    const bf16x8 qf = *(const bf16x8*)
        &qws[((size_t)(b * 256 + qc * 4 + w)) * 512 + lane * 8];

    f32x4 acc[4][4];
    #pragma unroll
    for (int i = 0; i < 4; i++)
        #pragma unroll
        for (int j = 0; j < 4; j++) acc[i][j] = (f32x4){0.f, 0.f, 0.f, 0.f};
    float lsum = 0.f;

    // fragment-packed K base for this (b, js): groups js*128 + tile*8 + jf
    const short* kfb = kws + ((size_t)(b * 256 + js * 128)) * 512;
    // tiled V: this wave's c-slice [64w, 64w+64) within each subtile
    const short* vbase = vws + ((size_t)((b * 2 + js) * 64)) * SUBT + w * 64 * 32;

    // swizzle: 16B unit u' = u ^ (row&7); row&7 == l16&7 for write row
    // (w*16+l16) and all read rows (qt*16+l16).
    const int swz   = l16 & 7;
    const int prowW = (w * 16 + l16) * 128 + (quad & 1) * 4;   // + u'*8

    // prologue: kf for tile 0 (8 j-frags x K=32), ping buffer
    bf16x8 kfA[8], kfB[8];
    #pragma unroll
    for (int jf = 0; jf < 8; jf++)
        kfA[jf] = *(const bf16x8*)(kfb + (size_t)jf * 512 + lane * 8);

    #pragma unroll 1
    for (int tile = 0; tile < NT2; tile += 2) {
        TILE_BODY(tile,     kfA, kfB, 0);
        TILE_BODY(tile + 1, kfB, kfA, 1);
    }

    // denominator partial for this wave's q over its full j half
    lsum += __shfl_xor(lsum, 16, 64);
    lsum += __shfl_xor(lsum, 32, 64);
    if (quad == 0) pl[(size_t)js * 16384 + (size_t)b * N_ + q] = lsum;

    // numerator partial: js0 -> fp32 into out, js1 -> bf16 into pnum1
    const int qq = qc * 64 + l16;
    if (js == 0) {
        float* ob = out + (size_t)b * C_ * N_;
        #pragma unroll
        for (int ct = 0; ct < 4; ++ct)
            #pragma unroll
            for (int qt = 0; qt < 4; ++qt)
                #pragma unroll
                for (int r = 0; r < 4; ++r) {
                    const int c = w * 64 + ct * 16 + quad * 4 + r;
                    ob[(size_t)c * N_ + qq + qt * 16] = acc[ct][qt][r];
                }
    } else {
        short* pb1 = pnum1 + (size_t)b * C_ * N_;
        #pragma unroll
        for (int ct = 0; ct < 4; ++ct)
            #pragma unroll
            for (int qt = 0; qt < 4; ++qt)
                #pragma unroll
                for (int r = 0; r < 4; ++r) {
                    const int c = w * 64 + ct * 16 + quad * 4 + r;
                    pb1[(size_t)c * N_ + qq + qt * 16] = f2bf(acc[ct][qt][r]);
                }
    }
}

// ---------------------------------------------------------------------------
// Kernel 3: combine (lred fused): linv = 1/(pl0+pl1) inline.
// out = g*(out + pnum1)*linv + x.
// ---------------------------------------------------------------------------
__global__ __launch_bounds__(256) void combine_kernel(
    const short* __restrict__ pnum1, const float* __restrict__ pl,
    const float* __restrict__ x, const float* __restrict__ gamma,
    float* __restrict__ out)
{
    const size_t i4 = ((size_t)blockIdx.x * 256 + threadIdx.x) * 4;   // < BCN
    const float4 nv = *(const float4*)(out + i4);
    const short4 n1 = *(const short4*)(pnum1 + i4);
    const float4 xv = *(const float4*)(x + i4);
    const int   bn  = (int)((i4 >> 20) * 4096 + (i4 & 4095));         // b*N + n
    const float4 p0 = *(const float4*)(pl + bn);
    const float4 p1 = *(const float4*)(pl + 16384 + bn);
    float4 lv;
    lv.x = 1.0f / (p0.x + p1.x);
    lv.y = 1.0f / (p0.y + p1.y);
    lv.z = 1.0f / (p0.z + p1.z);
    lv.w = 1.0f / (p0.w + p1.w);
    const float g0 = gamma[0];
    float4 o;
    o.x = g0 * ((nv.x + bf2f(n1.x)) * lv.x) + xv.x;
    o.y = g0 * ((nv.y + bf2f(n1.y)) * lv.y) + xv.y;
    o.z = g0 * ((nv.z + bf2f(n1.z)) * lv.z) + xv.z;
    o.w = g0 * ((nv.w + bf2f(n1.w)) * lv.w) + xv.w;
    *(float4*)(out + i4) = o;
}

extern "C" void kernel_launch(void* const* d_in, const int* in_sizes, int n_in,
                              void* d_out, int out_size, void* d_ws, size_t ws_size,
                              hipStream_t stream)
{
    const float* x     = (const float*)d_in[0];
    const float* Wq    = (const float*)d_in[1];
    const float* bq    = (const float*)d_in[2];
    const float* Wk    = (const float*)d_in[3];
    const float* bk    = (const float*)d_in[4];
    const float* Wv    = (const float*)d_in[5];
    const float* bv    = (const float*)d_in[6];
    const float* gamma = (const float*)d_in[7];
    float* out = (float*)d_out;

    // ws layout (proven-safe region sizes; xT slot now exclusively pnum1).
    char* base = (char*)d_ws;
    short* vws   = (short*)(base);                      // 8 MB  [8][64][256][32] tiled
    short* qws   = (short*)(base + 0x800000);           // 1 MB  [B][256 grp][512] packed
    short* kws   = (short*)(base + 0x900000);           // 1 MB  [B][256 grp][512] packed
    float* pl    = (float*)(base + 0xA00000);           // 128 KB [2][B*N]
    short* Wall  = (short*)(base + 0xA30000);           // 160 KB fragment-packed
    float* ball  = (float*)(base + 0xA58000);           // 1.25 KB
    short* pnum1 = (short*)(base + 0xA60000);           // 8 MB  [B][256][N]

    prep_kernel<<<41, 256, 0, stream>>>(Wq, bq, Wk, bk, Wv, bv, Wall, ball);
    proj_kernel<<<dim3(N_ / 64, B_), 256, 0, stream>>>(x, Wall, ball, qws, kws, vws);
    attn_kernel<<<512, 256, 0, stream>>>(qws, kws, vws, out, pnum1, pl);
    combine_kernel<<<4096, 256, 0, stream>>>(pnum1, pl, x, gamma, out);
}

// Round 10
// 143.408 us; speedup vs baseline: 2.4989x; 1.0060x over previous
//
#include <hip/hip_runtime.h>

#define B_   4
#define C_   256
#define C8_  32
#define N_   4096
#define JS   2                 // key split: js0 -> fp32 in d_out, js1 -> bf16 pnum1
#define NJ   (N_ / JS)         // 2048 keys per attn block
#define KB2  128               // j per tile
#define NT2  (NJ / KB2)        // 16 j-tiles per attn block
#define SUBT 8192              // shorts per V subtile: 256 c x 32 j
#define BCN  ((size_t)B_ * C_ * N_)   // 4,194,304

typedef __attribute__((ext_vector_type(8))) short bf16x8;
typedef __attribute__((ext_vector_type(4))) float f32x4;

__device__ inline short f2bf(float f) {
    union { float f; unsigned u; } v; v.f = f;
    unsigned r = v.u + 0x7FFFu + ((v.u >> 16) & 1u);   // RNE
    return (short)(r >> 16);
}
__device__ inline float bf2f(short s) {
    union { unsigned u; float f; } v; v.u = ((unsigned)(unsigned short)s) << 16;
    return v.f;
}

// ---------------------------------------------------------------------------
// Kernel 0: prep (tiny). blocks [0,40): W fp32 -> fragment-packed
// Wall[((gct*8+k)*4+quad)*16+l16)*8 + j] (one contiguous wave-store each).
// block 40: bias gather ball[320].
// ---------------------------------------------------------------------------
__global__ __launch_bounds__(256) void prep_kernel(
    const float* __restrict__ Wq, const float* __restrict__ bq,
    const float* __restrict__ Wk, const float* __restrict__ bk,
    const float* __restrict__ Wv, const float* __restrict__ bv,
    short* __restrict__ Wall, float* __restrict__ ball)
{
    const int blk = blockIdx.x;
    const int t   = threadIdx.x;
    if (blk < 40) {
        const int base = blk * 2048 + t * 8;            // 40*2048 = 320*256
        const int r = base >> 8, cc = base & 255;       // cc is 8-aligned
        const float* src = (r < 32) ? &Wq[r * C_ + cc]
                         : (r < 64) ? &Wk[(r - 32) * C_ + cc]
                                    : &Wv[(r - 64) * C_ + cc];
        const float4 a  = *(const float4*)src;
        const float4 b4 = *(const float4*)(src + 4);
        short4 s1, s2;
        s1.x = f2bf(a.x);  s1.y = f2bf(a.y);  s1.z = f2bf(a.z);  s1.w = f2bf(a.w);
        s2.x = f2bf(b4.x); s2.y = f2bf(b4.y); s2.z = f2bf(b4.z); s2.w = f2bf(b4.w);
        const int gct = r >> 4, l16w = r & 15;
        const int k   = cc >> 5, quad = (cc >> 3) & 3;
        short* d = &Wall[(((size_t)(gct * 8 + k) * 4 + quad) * 16 + l16w) * 8];
        *(short4*)d       = s1;
        *(short4*)(d + 4) = s2;
    } else {
        for (int i = t; i < 320; i += 256)
            ball[i] = (i < 32) ? bq[i] : (i < 64) ? bk[i - 32] : bv[i - 64];
    }
}

// ---------------------------------------------------------------------------
// Kernel 1: FUSED transpose + MFMA projections, v11. Grid (N/64, B),
// 1024 thr (16 waves = 4/SIMD; v10's 4 waves = 1/SIMD left every latency
// exposed -- proj was ~70us for ~6us of work). Wave (qtr=w>>2, nw=w&3):
// qtr owns 5 co-tiles, nw owns the 16-n group.
// V tiles use SWAPPED mfma(bfr, af): D fragment transposes to lane=co,
// rows=4 consecutive n -> V epilogue becomes short4 stores (64 scalar
// 64B-stride stores -> 16 vector stores; store-side segment-tax fix).
// Same products, same hw k-order => values bit-identical.
// ---------------------------------------------------------------------------
#define VSTORE(A, CT)                                                         \
  {                                                                           \
    const int co   = (CT) * 16 + l16;                                         \
    const float bs = ball[co];                                                \
    const int nb   = n0 + nw * 16 + quad * 4;                                 \
    const int js   = nb >> 11, sub = (nb >> 5) & 63, jj = nb & 31;            \
    short4 s;                                                                 \
    s.x = f2bf(A[0] + bs); s.y = f2bf(A[1] + bs);                             \
    s.z = f2bf(A[2] + bs); s.w = f2bf(A[3] + bs);                             \
    *(short4*)&vws[((size_t)((b * 2 + js) * 64 + sub)) * SUBT                 \
                   + (co - 64) * 32 + jj] = s;                                \
  }

__global__ __launch_bounds__(1024) void proj_kernel(
    const float* __restrict__ x, const short* __restrict__ Wall,
    const float* __restrict__ ball,
    short* __restrict__ qws, short* __restrict__ kws, short* __restrict__ vws)
{
    __shared__ short tilebf[256 * 68];   // 34.8 KB

    const int n0 = blockIdx.x * 64;
    const int b  = blockIdx.y;
    const int t  = threadIdx.x;
    const int w  = t >> 6, lane = t & 63, l16 = lane & 15, quad = lane >> 4;
    const int nw = w & 3, qtr = w >> 2;

    // phase 1: x (fp32) -> bf16 LDS tile [c][nl], 4 float4 per thread
    const float* xb = x + (size_t)b * C_ * N_ + n0;
    #pragma unroll
    for (int i = 0; i < 4; i++) {
        int e = t + i * 1024;                // 4096 float4 = 256 rows x 16
        int c = e >> 4, n4 = (e & 15) * 4;
        float4 v = *(const float4*)(xb + (size_t)c * N_ + n4);
        short4 s;
        s.x = f2bf(v.x); s.y = f2bf(v.y); s.z = f2bf(v.z); s.w = f2bf(v.w);
        *(short4*)&tilebf[c * 68 + n4] = s;
    }
    __syncthreads();

    // phase 2: bfr fragments (n = n0 + nw*16 + l16; c = k*32 + quad*8 + j)
    bf16x8 bfr[8];
    const int nl = nw * 16 + l16;
    #pragma unroll
    for (int k = 0; k < 8; k++) {
        bf16x8 f;
        #pragma unroll
        for (int j = 0; j < 8; j++)
            f[j] = tilebf[(k * 32 + quad * 8 + j) * 68 + nl];
        bfr[k] = f;
    }

    f32x4 acc[5];
    #pragma unroll
    for (int i = 0; i < 5; i++) acc[i] = (f32x4){0.f, 0.f, 0.f, 0.f};

    if (qtr == 0) {
        // ct 0..3 = q/k (normal orientation), ct 4 = first v tile (swapped)
        #pragma unroll
        for (int k = 0; k < 8; k++) {
            const bf16x8 bk = bfr[k];
            #pragma unroll
            for (int c5 = 0; c5 < 4; c5++) {
                const bf16x8 af = *(const bf16x8*)
                    &Wall[(size_t)(c5 * 8 + k) * 512 + lane * 8];
                acc[c5] = __builtin_amdgcn_mfma_f32_16x16x32_bf16(af, bk, acc[c5], 0, 0, 0);
            }
            const bf16x8 af4 = *(const bf16x8*)
                &Wall[(size_t)(4 * 8 + k) * 512 + lane * 8];
            acc[4] = __builtin_amdgcn_mfma_f32_16x16x32_bf16(bk, af4, acc[4], 0, 0, 0);
        }
    } else {
        const int ct0 = qtr * 5;
        #pragma unroll
        for (int k = 0; k < 8; k++) {
            const bf16x8 bk = bfr[k];
            #pragma unroll
            for (int c5 = 0; c5 < 5; c5++) {
                const bf16x8 af = *(const bf16x8*)
                    &Wall[(size_t)((ct0 + c5) * 8 + k) * 512 + lane * 8];
                acc[c5] = __builtin_amdgcn_mfma_f32_16x16x32_bf16(bk, af, acc[c5], 0, 0, 0);
            }
        }
    }

    const int grp = (n0 >> 4) + nw;          // = n>>4 for this wave

    if (qtr == 0) {
        // q (ct 0,1) and k (ct 2,3): fragment-packed stores (unchanged math)
        #pragma unroll
        for (int ct = 0; ct < 2; ct++) {
            const int cb = ct * 16 + quad * 4;
            short4 s;
            s.x = f2bf(acc[ct][0] + ball[cb + 0]);
            s.y = f2bf(acc[ct][1] + ball[cb + 1]);
            s.z = f2bf(acc[ct][2] + ball[cb + 2]);
            s.w = f2bf(acc[ct][3] + ball[cb + 3]);
            *(short4*)&qws[((size_t)(b * 256 + grp)) * 512
                           + (ct * 2 + (quad >> 1)) * 128 + l16 * 8 + (quad & 1) * 4] = s;
        }
        #pragma unroll
        for (int ct = 2; ct < 4; ct++) {
            const int cb = ct * 16 + quad * 4;
            short4 s;
            s.x = f2bf(acc[ct][0] + ball[cb + 0]);
            s.y = f2bf(acc[ct][1] + ball[cb + 1]);
            s.z = f2bf(acc[ct][2] + ball[cb + 2]);
            s.w = f2bf(acc[ct][3] + ball[cb + 3]);
            *(short4*)&kws[((size_t)(b * 256 + grp)) * 512
                           + ((ct - 2) * 2 + (quad >> 1)) * 128 + l16 * 8 + (quad & 1) * 4] = s;
        }
        VSTORE(acc[4], 4);
    } else {
        const int ct0 = qtr * 5;
        #pragma unroll
        for (int c5 = 0; c5 < 5; c5++) VSTORE(acc[c5], ct0 + c5);
    }
}

// ---------------------------------------------------------------------------
// Kernel 2: MFMA flash attention -- BYTE-IDENTICAL to the benched v10
// (53.2us, MfmaUtil 28%): this round's A/B control.
// ---------------------------------------------------------------------------
#define TILE_BODY(TILE, KC, KN, BUF)                                          \
  {                                                                           \
    const short* vb = vbase + (size_t)(TILE) * 4 * SUBT;                      \
    /* V ks0/ks1: issue early (covered by QK+exp+pack; no drain at barrier)*/ \
    bf16x8 vf0[4], vf1[4];                                                    \
    _Pragma("unroll") for (int ct = 0; ct < 4; ct++)                          \
      vf0[ct] = *(const bf16x8*)(vb + 0 * SUBT + (ct*16+l16)*32 + quad*8);    \
    _Pragma("unroll") for (int ct = 0; ct < 4; ct++)                          \
      vf1[ct] = *(const bf16x8*)(vb + 1 * SUBT + (ct*16+l16)*32 + quad*8);    \
    /* QK^T: S^T[j][q] for this wave's 16 q over 128 j */                     \
    f32x4 s[8];                                                               \
    _Pragma("unroll") for (int jf = 0; jf < 8; jf++)                          \
      s[jf] = __builtin_amdgcn_mfma_f32_16x16x32_bf16(KC[jf], qf,             \
              (f32x4){0.f,0.f,0.f,0.f}, 0, 0, 0);                             \
    /* K prefetch for next tile (contiguous 1KB fragment loads) */            \
    {                                                                         \
      const int tn = ((TILE) + 1 < NT2) ? (TILE) + 1 : (TILE);                \
      const short* kb = kfb + (size_t)(tn * 8) * 512;                         \
      _Pragma("unroll") for (int jf = 0; jf < 8; jf++)                        \
        KN[jf] = *(const bf16x8*)(kb + (size_t)jf * 512 + lane * 8);          \
    }                                                                         \
    /* softmax numerator (no max: scores bounded ~O(3)), pack, publish */     \
    _Pragma("unroll") for (int jf = 0; jf < 8; jf++) {                        \
      float p0 = __expf(s[jf][0]); float p1 = __expf(s[jf][1]);               \
      float p2 = __expf(s[jf][2]); float p3 = __expf(s[jf][3]);               \
      lsum += p0 + p1 + p2 + p3;                                              \
      short4 pa; pa.x = f2bf(p0); pa.y = f2bf(p1);                            \
      pa.z = f2bf(p2); pa.w = f2bf(p3);                                       \
      const int u = (jf * 2 + (quad >> 1)) ^ swz;                             \
      *(short4*)&Plds[BUF][prowW + u * 8] = pa;                               \
    }                                                                         \
    /* publish P: wait LDS writes only; vmcnt stays in flight (T4) */         \
    asm volatile("s_waitcnt lgkmcnt(0)" ::: "memory");                        \
    __builtin_amdgcn_s_barrier();                                             \
    asm volatile("" ::: "memory");                                            \
    bf16x8 vf2[4];                                                            \
    _Pragma("unroll") for (int ct = 0; ct < 4; ct++)                          \
      vf2[ct] = *(const bf16x8*)(vb + 2 * SUBT + (ct*16+l16)*32 + quad*8);    \
    __builtin_amdgcn_s_setprio(1);                                            \
    /* PV ks0 */                                                              \
    _Pragma("unroll") for (int qt = 0; qt < 4; ++qt) {                        \
      const bf16x8 pf = *(const bf16x8*)                                      \
        &Plds[BUF][(qt*16+l16)*128 + ((0*4+quad)^swz)*8];                     \
      _Pragma("unroll") for (int ct = 0; ct < 4; ++ct)                        \
        acc[ct][qt] = __builtin_amdgcn_mfma_f32_16x16x32_bf16(                \
            vf0[ct], pf, acc[ct][qt], 0, 0, 0);                               \
    }                                                                         \
    bf16x8 vf3[4];                                                            \
    _Pragma("unroll") for (int ct = 0; ct < 4; ct++)                          \
      vf3[ct] = *(const bf16x8*)(vb + 3 * SUBT + (ct*16+l16)*32 + quad*8);    \
    /* PV ks1 */                                                              \
    _Pragma("unroll") for (int qt = 0; qt < 4; ++qt) {                        \
      const bf16x8 pf = *(const bf16x8*)                                      \
        &Plds[BUF][(qt*16+l16)*128 + ((1*4+quad)^swz)*8];                     \
      _Pragma("unroll") for (int ct = 0; ct < 4; ++ct)                        \
        acc[ct][qt] = __builtin_amdgcn_mfma_f32_16x16x32_bf16(                \
            vf1[ct], pf, acc[ct][qt], 0, 0, 0);                               \
    }                                                                         \
    /* PV ks2 */                                                              \
    _Pragma("unroll") for (int qt = 0; qt < 4; ++qt) {                        \
      const bf16x8 pf = *(const bf16x8*)                                      \
        &Plds[BUF][(qt*16+l16)*128 + ((2*4+quad)^swz)*8];                     \
      _Pragma("unroll") for (int ct = 0; ct < 4; ++ct)                        \
        acc[ct][qt] = __builtin_amdgcn_mfma_f32_16x16x32_bf16(                \
            vf2[ct], pf, acc[ct][qt], 0, 0, 0);                               \
    }                                                                         \
    /* PV ks3 */                                                              \
    _Pragma("unroll") for (int qt = 0; qt < 4; ++qt) {                        \
      const bf16x8 pf = *(const bf16x8*)                                      \
        &Plds[BUF][(qt*16+l16)*128 + ((3*4+quad)^swz)*8];                     \
      _Pragma("unroll") for (int ct = 0; ct < 4; ++ct)                        \
        acc[ct][qt] = __builtin_amdgcn_mfma_f32_16x16x32_bf16(                \
            vf3[ct], pf, acc[ct][qt], 0, 0, 0);                               \
    }                                                                         \
    __builtin_amdgcn_s_setprio(0);                                            \
  }

__global__ __launch_bounds__(256, 2) void attn_kernel(
    const short* __restrict__ qws, const short* __restrict__ kws,
    const short* __restrict__ vws,
    float* __restrict__ out, short* __restrict__ pnum1, float* __restrict__ pl)
{
    __shared__ short Plds[2][64 * 128];   // 2 x 16 KB

    const int blk = blockIdx.x;
    const int b   = blk & 3;
    const int js  = (blk >> 2) & 1;
    const int qc  = blk >> 3;            // 0..63
    const int t   = threadIdx.x;
    const int w   = t >> 6, lane = t & 63, l16 = lane & 15, quad = lane >> 4;
    const int q   = qc * 64 + w * 16 + l16;   // QK-duty q row for this lane

    // Q from fragment-packed qws: group qc*4+w, contiguous 1KB per wave
    const bf16x8 qf = *(const bf16x8*)
        &qws[((size_t)(b * 256 + qc * 4 + w)) * 512 + lane * 8];

    f32x4 acc[4][4];
    #pragma unroll
    for (int i = 0; i < 4; i++)
        #pragma unroll
        for (int j = 0; j < 4; j++) acc[i][j] = (f32x4){0.f, 0.f, 0.f, 0.f};
    float lsum = 0.f;

    // fragment-packed K base for this (b, js): groups js*128 + tile*8 + jf
    const short* kfb = kws + ((size_t)(b * 256 + js * 128)) * 512;
    // tiled V: this wave's c-slice [64w, 64w+64) within each subtile
    const short* vbase = vws + ((size_t)((b * 2 + js) * 64)) * SUBT + w * 64 * 32;

    // swizzle: 16B unit u' = u ^ (row&7); row&7 == l16&7 for write row
    // (w*16+l16) and all read rows (qt*16+l16).
    const int swz   = l16 & 7;
    const int prowW = (w * 16 + l16) * 128 + (quad & 1) * 4;   // + u'*8

    // prologue: kf for tile 0 (8 j-frags x K=32), ping buffer
    bf16x8 kfA[8], kfB[8];
    #pragma unroll
    for (int jf = 0; jf < 8; jf++)
        kfA[jf] = *(const bf16x8*)(kfb + (size_t)jf * 512 + lane * 8);

    #pragma unroll 1
    for (int tile = 0; tile < NT2; tile += 2) {
        TILE_BODY(tile,     kfA, kfB, 0);
        TILE_BODY(tile + 1, kfB, kfA, 1);
    }

    // denominator partial for this wave's q over its full j half
    lsum += __shfl_xor(lsum, 16, 64);
    lsum += __shfl_xor(lsum, 32, 64);
    if (quad == 0) pl[(size_t)js * 16384 + (size_t)b * N_ + q] = lsum;

    // numerator partial: js0 -> fp32 into out, js1 -> bf16 into pnum1
    const int qq = qc * 64 + l16;
    if (js == 0) {
        float* ob = out + (size_t)b * C_ * N_;
        #pragma unroll
        for (int ct = 0; ct < 4; ++ct)
            #pragma unroll
            for (int qt = 0; qt < 4; ++qt)
                #pragma unroll
                for (int r = 0; r < 4; ++r) {
                    const int c = w * 64 + ct * 16 + quad * 4 + r;
                    ob[(size_t)c * N_ + qq + qt * 16] = acc[ct][qt][r];
                }
    } else {
        short* pb1 = pnum1 + (size_t)b * C_ * N_;
        #pragma unroll
        for (int ct = 0; ct < 4; ++ct)
            #pragma unroll
            for (int qt = 0; qt < 4; ++qt)
                #pragma unroll
                for (int r = 0; r < 4; ++r) {
                    const int c = w * 64 + ct * 16 + quad * 4 + r;
                    pb1[(size_t)c * N_ + qq + qt * 16] = f2bf(acc[ct][qt][r]);
                }
    }
}

// ---------------------------------------------------------------------------
// Kernel 3: combine (lred fused): linv = 1/(pl0+pl1) inline.
// out = g*(out + pnum1)*linv + x.
// ---------------------------------------------------------------------------
__global__ __launch_bounds__(256) void combine_kernel(
    const short* __restrict__ pnum1, const float* __restrict__ pl,
    const float* __restrict__ x, const float* __restrict__ gamma,
    float* __restrict__ out)
{
    const size_t i4 = ((size_t)blockIdx.x * 256 + threadIdx.x) * 4;   // < BCN
    const float4 nv = *(const float4*)(out + i4);
    const short4 n1 = *(const short4*)(pnum1 + i4);
    const float4 xv = *(const float4*)(x + i4);
    const int   bn  = (int)((i4 >> 20) * 4096 + (i4 & 4095));         // b*N + n
    const float4 p0 = *(const float4*)(pl + bn);
    const float4 p1 = *(const float4*)(pl + 16384 + bn);
    float4 lv;
    lv.x = 1.0f / (p0.x + p1.x);
    lv.y = 1.0f / (p0.y + p1.y);
    lv.z = 1.0f / (p0.z + p1.z);
    lv.w = 1.0f / (p0.w + p1.w);
    const float g0 = gamma[0];
    float4 o;
    o.x = g0 * ((nv.x + bf2f(n1.x)) * lv.x) + xv.x;
    o.y = g0 * ((nv.y + bf2f(n1.y)) * lv.y) + xv.y;
    o.z = g0 * ((nv.z + bf2f(n1.z)) * lv.z) + xv.z;
    o.w = g0 * ((nv.w + bf2f(n1.w)) * lv.w) + xv.w;
    *(float4*)(out + i4) = o;
}

extern "C" void kernel_launch(void* const* d_in, const int* in_sizes, int n_in,
                              void* d_out, int out_size, void* d_ws, size_t ws_size,
                              hipStream_t stream)
{
    const float* x     = (const float*)d_in[0];
    const float* Wq    = (const float*)d_in[1];
    const float* bq    = (const float*)d_in[2];
    const float* Wk    = (const float*)d_in[3];
    const float* bk    = (const float*)d_in[4];
    const float* Wv    = (const float*)d_in[5];
    const float* bv    = (const float*)d_in[6];
    const float* gamma = (const float*)d_in[7];
    float* out = (float*)d_out;

    // ws layout (proven-safe region sizes).
    char* base = (char*)d_ws;
    short* vws   = (short*)(base);                      // 8 MB  [8][64][256][32] tiled
    short* qws   = (short*)(base + 0x800000);           // 1 MB  [B][256 grp][512] packed
    short* kws   = (short*)(base + 0x900000);           // 1 MB  [B][256 grp][512] packed
    float* pl    = (float*)(base + 0xA00000);           // 128 KB [2][B*N]
    short* Wall  = (short*)(base + 0xA30000);           // 160 KB fragment-packed
    float* ball  = (float*)(base + 0xA58000);           // 1.25 KB
    short* pnum1 = (short*)(base + 0xA60000);           // 8 MB  [B][256][N]

    prep_kernel<<<41, 256, 0, stream>>>(Wq, bq, Wk, bk, Wv, bv, Wall, ball);
    proj_kernel<<<dim3(N_ / 64, B_), 1024, 0, stream>>>(x, Wall, ball, qws, kws, vws);
    attn_kernel<<<512, 256, 0, stream>>>(qws, kws, vws, out, pnum1, pl);
    combine_kernel<<<4096, 256, 0, stream>>>(pnum1, pl, x, gamma, out);
}